// Round 1
// baseline (2430.833 us; speedup 1.0000x reference)
//
#include <hip/hip_runtime.h>

typedef unsigned short u16;
typedef __attribute__((ext_vector_type(4))) float f32x4;
typedef __attribute__((ext_vector_type(8))) __bf16 bf16x8;
typedef __attribute__((ext_vector_type(4))) unsigned short u16x4;
typedef __attribute__((ext_vector_type(8))) unsigned short u16x8;

#define DEV static __device__ __forceinline__

// ---------------------------------------------------------------------------
// Problem constants: B=16,T=12,NN=325,GP=64,D=512,H=8,HD=64,N_TOT=389
//   BT=192, MG=BT*64=12288 (glob rows), MP=BT*325=62400 (patch rows),
//   MKV=BT*389=74688 (x_kv rows). All GEMMs: C = A(bf16,MxK) @ Wt(bf16,NxK)^T.
// ---------------------------------------------------------------------------

DEV u16 f2b(float f) {               // fp32 -> bf16 bits, round-to-nearest-even
  union { float f; unsigned u; } c; c.f = f;
  return (u16)((c.u + 0x7FFFu + ((c.u >> 16) & 1u)) >> 16);
}

DEV void async_cp16(void* lds, const void* g) {   // global->LDS, 16B/lane
  __builtin_amdgcn_global_load_lds((__attribute__((address_space(1))) void*)g,
                                   (__attribute__((address_space(3))) void*)lds,
                                   16, 0, 0);
}

// ---------------------------------------------------------------------------
// Weight transpose + bf16 cast:  W(KxN f32) -> Wt(NxK bf16)
// ---------------------------------------------------------------------------
__global__ __launch_bounds__(256) void transpose_w(const float* __restrict__ W,
                                                   u16* __restrict__ Wt,
                                                   int K, int N) {
  __shared__ float t[32][33];
  const int n0 = blockIdx.x * 32, k0 = blockIdx.y * 32;
  const int tx = threadIdx.x, ty = threadIdx.y;
  for (int i = ty; i < 32; i += 8) t[i][tx] = W[(size_t)(k0 + i) * N + n0 + tx];
  __syncthreads();
  for (int i = ty; i < 32; i += 8)
    Wt[(size_t)(n0 + i) * K + k0 + tx] = f2b(t[tx][i]);
}

// ---------------------------------------------------------------------------
// X(f32, [bt][389][512]) -> Xg(bf16 [bt*64][512]) + Xp(bf16 [bt*325][512])
// ---------------------------------------------------------------------------
__global__ __launch_bounds__(256) void convert_x(const float* __restrict__ X,
                                                 u16* __restrict__ Xg,
                                                 u16* __restrict__ Xp) {
  const size_t i = ((size_t)blockIdx.x * 256 + threadIdx.x) * 4;
  const f32x4 v = *(const f32x4*)(X + i);
  const size_t row = i >> 9;
  const int col = (int)(i & 511);
  const int bt = (int)(row / 389), n = (int)(row - (size_t)bt * 389);
  u16x4 w;
#pragma unroll
  for (int u = 0; u < 4; u++) w[u] = f2b(v[u]);
  u16* dst = (n < 64) ? (Xg + (((size_t)bt * 64 + n) << 9) + col)
                      : (Xp + (((size_t)bt * 325 + (n - 64)) << 9) + col);
  *(u16x4*)dst = w;
}

// ---------------------------------------------------------------------------
// GEMM: C = A @ Wt^T + bias.  128x128 tile, 256 thr (4 waves, 2x2 of 64x64),
// BK=32, global_load_lds(16B) staging, mfma_f32_16x16x32_bf16.
// Epilogue MODEs:
//  0: bf16 row-major            1: bf16, row -> bt*389+ofs+rr (x_kv build)
//  2: f32 -> d_out t-rows + bf16 copy   3: f32 row-major
//  4: bf16 + relu               5: f32 accumulate (+=)
//  6: bf16 V^T scatter: [bt][h][d][kv] stride vt_stride
// ---------------------------------------------------------------------------
template <int MODE>
__global__ __launch_bounds__(256) void gemm_bt(
    const u16* __restrict__ A, const u16* __restrict__ Bt,
    const float* __restrict__ bias, float* outF, u16* outB,
    int M, int N, int K, int rows_per, int row_ofs, int vt_stride) {
  __shared__ u16 As[128 * 32];
  __shared__ u16 Bs[128 * 32];
  const int tid = threadIdx.x;
  const int lane = tid & 63, wid = tid >> 6;
  const int l4 = lane >> 4, l16 = lane & 15;
  const int m0 = blockIdx.x * 128, n0 = blockIdx.y * 128;
  const int wr = (wid >> 1) * 64, wc = (wid & 1) * 64;

  const u16* gA = A + (size_t)(m0 + wid * 32 + (lane >> 2)) * K + (lane & 3) * 8;
  const u16* gB = Bt + (size_t)(n0 + wid * 32 + (lane >> 2)) * K + (lane & 3) * 8;
  u16* lA0 = As + (wid * 32) * 32;
  u16* lA1 = As + (wid * 32 + 16) * 32;
  u16* lB0 = Bs + (wid * 32) * 32;
  u16* lB1 = Bs + (wid * 32 + 16) * 32;

  f32x4 acc[4][4] = {};

  for (int kk = 0; kk < K; kk += 32) {
    if (kk) __syncthreads();
    async_cp16(lA0, gA + kk);
    async_cp16(lA1, gA + (size_t)16 * K + kk);
    async_cp16(lB0, gB + kk);
    async_cp16(lB1, gB + (size_t)16 * K + kk);
    __syncthreads();
    bf16x8 af[4], bfr[4];
#pragma unroll
    for (int i = 0; i < 4; i++)
      af[i] = *(const bf16x8*)(As + (wr + i * 16 + l16) * 32 + l4 * 8);
#pragma unroll
    for (int j = 0; j < 4; j++)
      bfr[j] = *(const bf16x8*)(Bs + (wc + j * 16 + l16) * 32 + l4 * 8);
#pragma unroll
    for (int i = 0; i < 4; i++)
#pragma unroll
      for (int j = 0; j < 4; j++)
        acc[i][j] = __builtin_amdgcn_mfma_f32_16x16x32_bf16(af[i], bfr[j],
                                                            acc[i][j], 0, 0, 0);
  }

#pragma unroll
  for (int j = 0; j < 4; j++) {
    const int col = n0 + wc + j * 16 + l16;
    const float bv = bias[col];
#pragma unroll
    for (int i = 0; i < 4; i++) {
#pragma unroll
      for (int r = 0; r < 4; r++) {
        const int row = m0 + wr + i * 16 + l4 * 4 + r;   // C layout: m89/m91
        if (row >= M) continue;
        const float v = acc[i][j][r] + bv;
        if constexpr (MODE == 0) {
          outB[(size_t)row * N + col] = f2b(v);
        } else if constexpr (MODE == 1) {
          const int bt = row / rows_per, rr = row - bt * rows_per;
          outB[((size_t)bt * 389 + row_ofs + rr) * 512 + col] = f2b(v);
        } else if constexpr (MODE == 2) {
          const int bt = row >> 6, rr = row & 63;
          outF[((size_t)bt * 389 + rr) * 512 + col] = v;
          outB[(size_t)row * 512 + col] = f2b(v);
        } else if constexpr (MODE == 3) {
          outF[(size_t)row * N + col] = v;
        } else if constexpr (MODE == 4) {
          outB[(size_t)row * N + col] = f2b(v > 0.f ? v : 0.f);
        } else if constexpr (MODE == 5) {
          outF[(size_t)row * N + col] += v;
        } else {  // MODE 6: V^T
          const int bt = row / rows_per, rr = row - bt * rows_per;
          const int h = col >> 6, d = col & 63;
          outB[(((size_t)bt * 8 + h) * 64 + d) * (size_t)vt_stride +
               (row_ofs + rr)] = f2b(v);
        }
      }
    }
  }
}

// ---------------------------------------------------------------------------
// Fused attention: block=(bt,head), 4 waves x 16 q-rows per chunk.
// S = Q K^T * 0.125 (MFMA from global), in-reg softmax (16-lane shfl),
// P -> LDS bf16, PV = P @ V via pre-transposed Vt[bt][h][d][kv].
// NKP = padded key count (mult of 32); cols >= NK masked to -1e30 -> P=0.
// ---------------------------------------------------------------------------
template <int MQ, int NK, int NKP>
__global__ __launch_bounds__(256) void attn_fused(const u16* __restrict__ Q,
                                                  const u16* __restrict__ Kb,
                                                  const u16* __restrict__ Vt,
                                                  u16* __restrict__ O) {
  constexpr int NT = NKP / 16;
  constexpr int QC = (MQ + 63) / 64;
  __shared__ u16 Pl[4][16 * NKP];
  const int tid = threadIdx.x, lane = tid & 63, wid = tid >> 6;
  const int l4 = lane >> 4, l16 = lane & 15;
  const int bt = blockIdx.x >> 3, h = blockIdx.x & 7;

  for (int qc = 0; qc < QC; ++qc) {
    const int q0 = qc * 64 + wid * 16;
    const u16* qp = Q + ((size_t)bt * MQ + q0 + l16) * 512 + h * 64 + l4 * 8;
    const bf16x8 aq0 = *(const bf16x8*)qp;
    const bf16x8 aq1 = *(const bf16x8*)(qp + 32);

    f32x4 s[NT];
#pragma unroll
    for (int t = 0; t < NT; t++) {
      const u16* kp =
          Kb + ((size_t)bt * NK + t * 16 + l16) * 512 + h * 64 + l4 * 8;
      f32x4 a = {0.f, 0.f, 0.f, 0.f};
      a = __builtin_amdgcn_mfma_f32_16x16x32_bf16(aq0, *(const bf16x8*)kp, a,
                                                  0, 0, 0);
      a = __builtin_amdgcn_mfma_f32_16x16x32_bf16(aq1, *(const bf16x8*)(kp + 32),
                                                  a, 0, 0, 0);
      const bool valid = (t * 16 + l16) < NK;
#pragma unroll
      for (int r = 0; r < 4; r++) s[t][r] = valid ? a[r] * 0.125f : -1e30f;
    }
    f32x4 mx = s[0];
#pragma unroll
    for (int t = 1; t < NT; t++)
#pragma unroll
      for (int r = 0; r < 4; r++) mx[r] = fmaxf(mx[r], s[t][r]);
#pragma unroll
    for (int m = 1; m < 16; m <<= 1)
#pragma unroll
      for (int r = 0; r < 4; r++) mx[r] = fmaxf(mx[r], __shfl_xor(mx[r], m));
    f32x4 sum = {0.f, 0.f, 0.f, 0.f};
#pragma unroll
    for (int t = 0; t < NT; t++)
#pragma unroll
      for (int r = 0; r < 4; r++) {
        const float e = __expf(s[t][r] - mx[r]);
        s[t][r] = e;
        sum[r] += e;
      }
#pragma unroll
    for (int m = 1; m < 16; m <<= 1)
#pragma unroll
      for (int r = 0; r < 4; r++) sum[r] += __shfl_xor(sum[r], m);

    u16* pw = &Pl[wid][0];
#pragma unroll
    for (int t = 0; t < NT; t++)
#pragma unroll
      for (int r = 0; r < 4; r++)
        pw[(l4 * 4 + r) * NKP + t * 16 + l16] = f2b(s[t][r]);

    __syncthreads();

    f32x4 o[4] = {};
    const u16* vbase = Vt + ((size_t)bt * 8 + h) * 64 * NKP;
#pragma unroll
    for (int ks = 0; ks < NKP / 32; ks++) {
      const bf16x8 ap = *(const bf16x8*)(&Pl[wid][l16 * NKP + ks * 32 + l4 * 8]);
#pragma unroll
      for (int j = 0; j < 4; j++) {
        const bf16x8 bv = *(const bf16x8*)(vbase + (size_t)(j * 16 + l16) * NKP +
                                           ks * 32 + l4 * 8);
        o[j] = __builtin_amdgcn_mfma_f32_16x16x32_bf16(ap, bv, o[j], 0, 0, 0);
      }
    }
#pragma unroll
    for (int j = 0; j < 4; j++)
#pragma unroll
      for (int r = 0; r < 4; r++) {
        const int qr = q0 + l4 * 4 + r;
        if (qr < MQ)
          O[((size_t)bt * MQ + qr) * 512 + h * 64 + j * 16 + l16] =
              f2b(o[j][r] / sum[r]);
      }
    __syncthreads();
  }
}

// ---------------------------------------------------------------------------
// LN1: y = LN(X_patch + add) (in-place over add is safe: per-lane RAW only)
// ---------------------------------------------------------------------------
__global__ __launch_bounds__(256) void ln_res(const float* X, const float* add,
                                              const float* g, const float* b,
                                              float* y, u16* yb) {
  const int p = blockIdx.x * 4 + (threadIdx.x >> 6);
  const int lane = threadIdx.x & 63;
  const int bt = p / 325, n = p - bt * 325;
  const float* xr = X + ((size_t)bt * 389 + 64 + n) * 512 + lane * 8;
  const float* ar = add + (size_t)p * 512 + lane * 8;
  float vv[8];
  {
    const f32x4 a0 = *(const f32x4*)xr, a1 = *(const f32x4*)(xr + 4);
    const f32x4 b0 = *(const f32x4*)ar, b1 = *(const f32x4*)(ar + 4);
#pragma unroll
    for (int u = 0; u < 4; u++) {
      vv[u] = a0[u] + b0[u];
      vv[u + 4] = a1[u] + b1[u];
    }
  }
  float s1 = 0.f, s2 = 0.f;
#pragma unroll
  for (int u = 0; u < 8; u++) {
    s1 += vv[u];
    s2 += vv[u] * vv[u];
  }
  for (int m = 1; m < 64; m <<= 1) {
    s1 += __shfl_xor(s1, m);
    s2 += __shfl_xor(s2, m);
  }
  const float mean = s1 * (1.f / 512.f);
  const float inv = rsqrtf(s2 * (1.f / 512.f) - mean * mean + 1e-5f);
  const int c0 = lane * 8;
  f32x4 o0, o1;
  u16x8 ob;
#pragma unroll
  for (int u = 0; u < 8; u++) {
    const float o = (vv[u] - mean) * inv * g[c0 + u] + b[c0 + u];
    if (u < 4) o0[u] = o; else o1[u - 4] = o;
    ob[u] = f2b(o);
  }
  *(f32x4*)(y + (size_t)p * 512 + c0) = o0;
  *(f32x4*)(y + (size_t)p * 512 + c0 + 4) = o1;
  *(u16x8*)(yb + (size_t)p * 512 + c0) = ob;
}

// LN2: d_out patch rows = LN(y)
__global__ __launch_bounds__(256) void ln_out(const float* y, const float* g,
                                              const float* b, float* out) {
  const int p = blockIdx.x * 4 + (threadIdx.x >> 6);
  const int lane = threadIdx.x & 63;
  const int bt = p / 325, n = p - bt * 325;
  const float* yr = y + (size_t)p * 512 + lane * 8;
  float vv[8];
  {
    const f32x4 a0 = *(const f32x4*)yr, a1 = *(const f32x4*)(yr + 4);
#pragma unroll
    for (int u = 0; u < 4; u++) {
      vv[u] = a0[u];
      vv[u + 4] = a1[u];
    }
  }
  float s1 = 0.f, s2 = 0.f;
#pragma unroll
  for (int u = 0; u < 8; u++) {
    s1 += vv[u];
    s2 += vv[u] * vv[u];
  }
  for (int m = 1; m < 64; m <<= 1) {
    s1 += __shfl_xor(s1, m);
    s2 += __shfl_xor(s2, m);
  }
  const float mean = s1 * (1.f / 512.f);
  const float inv = rsqrtf(s2 * (1.f / 512.f) - mean * mean + 1e-5f);
  const int c0 = lane * 8;
  f32x4 o0, o1;
#pragma unroll
  for (int u = 0; u < 8; u++) {
    const float o = (vv[u] - mean) * inv * g[c0 + u] + b[c0 + u];
    if (u < 4) o0[u] = o; else o1[u - 4] = o;
  }
  float* orow = out + ((size_t)bt * 389 + 64 + n) * 512 + c0;
  *(f32x4*)(orow) = o0;
  *(f32x4*)(orow + 4) = o1;
}

// ---------------------------------------------------------------------------
extern "C" void kernel_launch(void* const* d_in, const int* in_sizes, int n_in,
                              void* d_out, int out_size, void* d_ws,
                              size_t ws_size, hipStream_t stream) {
  (void)in_sizes; (void)n_in; (void)out_size; (void)ws_size;
  const float* X = (const float*)d_in[0];
  const float* W[8] = {(const float*)d_in[1],  (const float*)d_in[3],
                       (const float*)d_in[5],  (const float*)d_in[7],
                       (const float*)d_in[9],  (const float*)d_in[11],
                       (const float*)d_in[13], (const float*)d_in[15]};
  const float* Bv[8] = {(const float*)d_in[2],  (const float*)d_in[4],
                        (const float*)d_in[6],  (const float*)d_in[8],
                        (const float*)d_in[10], (const float*)d_in[12],
                        (const float*)d_in[14], (const float*)d_in[16]};
  const float* ff_w1 = (const float*)d_in[17];
  const float* ff_b1 = (const float*)d_in[18];
  const float* ff_w2 = (const float*)d_in[19];
  const float* ff_b2 = (const float*)d_in[20];
  const float* ln1_g = (const float*)d_in[21];
  const float* ln1_b = (const float*)d_in[22];
  const float* ln2_g = (const float*)d_in[23];
  const float* ln2_b = (const float*)d_in[24];
  float* out = (float*)d_out;
  char* ws = (char*)d_ws;

  constexpr size_t MG = 12288, MP = 62400, MKV = 74688, PADR = 128;
  const size_t szQe = (MG + PADR) * 1024;                 // bf16 rows*512*2
  const size_t szKe = (MP + PADR) * 1024;
  const size_t szVte = (size_t)192 * 8 * 64 * 352 * 2;
  const size_t szKd = (MKV + PADR) * 1024;
  const size_t szVtd = (size_t)192 * 8 * 64 * 416 * 2;
  const size_t szY = MP * 2048;                           // f32 62400x512
  const size_t szH = (size_t)(15616 + PADR) * 2048 * 2;

  // Arenas (lifetime-disjoint reuse; peak ~423 MB):
  size_t off = 0;
  const size_t o_wt = off; off += (size_t)4194304 * 2;    // 10 bf16 W^T
  const size_t o_AD = off; off += szY;                    // Xg+Xp, later y
  size_t b1 = szQe + szKe + szVte;                        // enc Q/K/Vt
  size_t b2 = szKe + szKd + szVtd;                        // dec Q/K/Vt
  size_t b3 = szKe + szH;                                 // yb + h
  size_t szB = b1 > b2 ? b1 : b2; if (b3 > szB) szB = b3;
  const size_t o_B = off; off += szB;
  const size_t o_C = off; off += szKe;                    // attn_e+tb | attn_d

  u16* wt = (u16*)(ws + o_wt);
  u16* Xg = (u16*)(ws + o_AD);
  u16* Xp = (u16*)(ws + o_AD + szQe);
  float* y = (float*)(ws + o_AD);
  u16* Qe = (u16*)(ws + o_B);
  u16* Ke = (u16*)(ws + o_B + szQe);
  u16* Vte = (u16*)(ws + o_B + szQe + szKe);
  u16* Qd = (u16*)(ws + o_B);
  u16* Kd = (u16*)(ws + o_B + szKe);
  u16* Vtd = (u16*)(ws + o_B + szKe + szKd);
  u16* yb = (u16*)(ws + o_B);
  u16* hb = (u16*)(ws + o_B + szKe);
  u16* attn_e = (u16*)(ws + o_C);
  u16* tb = (u16*)(ws + o_C + szQe);
  u16* attn_d = (u16*)(ws + o_C);

  u16* wt_p[8];
  for (int i = 0; i < 8; i++) wt_p[i] = wt + (size_t)i * 262144;
  u16* ff1t = wt + (size_t)8 * 262144;
  u16* ff2t = ff1t + (size_t)1048576;

  dim3 tblk(32, 8);
  for (int i = 0; i < 8; i++)
    transpose_w<<<dim3(16, 16), tblk, 0, stream>>>(W[i], wt_p[i], 512, 512);
  transpose_w<<<dim3(64, 16), tblk, 0, stream>>>(ff_w1, ff1t, 512, 2048);
  transpose_w<<<dim3(16, 64), tblk, 0, stream>>>(ff_w2, ff2t, 2048, 512);

  convert_x<<<37344, 256, 0, stream>>>(X, Xg, Xp);

  // Encoder
  gemm_bt<0><<<dim3(96, 4), 256, 0, stream>>>(Xg, wt_p[0], Bv[0], nullptr, Qe,
                                              (int)MG, 512, 512, 0, 0, 0);
  gemm_bt<0><<<dim3(488, 4), 256, 0, stream>>>(Xp, wt_p[1], Bv[1], nullptr, Ke,
                                               (int)MP, 512, 512, 0, 0, 0);
  gemm_bt<6><<<dim3(488, 4), 256, 0, stream>>>(Xp, wt_p[2], Bv[2], nullptr, Vte,
                                               (int)MP, 512, 512, 325, 0, 352);
  attn_fused<64, 325, 352><<<1536, 256, 0, stream>>>(Qe, Ke, Vte, attn_e);
  gemm_bt<2><<<dim3(96, 4), 256, 0, stream>>>(attn_e, wt_p[3], Bv[3], out, tb,
                                              (int)MG, 512, 512, 0, 0, 0);

  // Decoder (x_kv = [t ; patch] built via row-remap epilogues)
  gemm_bt<0><<<dim3(488, 4), 256, 0, stream>>>(Xp, wt_p[4], Bv[4], nullptr, Qd,
                                               (int)MP, 512, 512, 0, 0, 0);
  gemm_bt<1><<<dim3(96, 4), 256, 0, stream>>>(tb, wt_p[5], Bv[5], nullptr, Kd,
                                              (int)MG, 512, 512, 64, 0, 0);
  gemm_bt<1><<<dim3(488, 4), 256, 0, stream>>>(Xp, wt_p[5], Bv[5], nullptr, Kd,
                                               (int)MP, 512, 512, 325, 64, 0);
  gemm_bt<6><<<dim3(96, 4), 256, 0, stream>>>(tb, wt_p[6], Bv[6], nullptr, Vtd,
                                              (int)MG, 512, 512, 64, 0, 416);
  gemm_bt<6><<<dim3(488, 4), 256, 0, stream>>>(Xp, wt_p[6], Bv[6], nullptr, Vtd,
                                               (int)MP, 512, 512, 325, 64, 416);
  attn_fused<325, 389, 416><<<1536, 256, 0, stream>>>(Qd, Kd, Vtd, attn_d);
  gemm_bt<3><<<dim3(488, 4), 256, 0, stream>>>(attn_d, wt_p[7], Bv[7], y,
                                               nullptr, (int)MP, 512, 512, 0, 0,
                                               0);

  // LN1 (residual with original fp32 patch), then FF chunked x4, then LN2.
  ln_res<<<15600, 256, 0, stream>>>(X, y, ln1_g, ln1_b, y, yb);

  const int c0s[4] = {0, 15616, 31232, 46848};
  const int mcs[4] = {15616, 15616, 15616, 15552};
  for (int c = 0; c < 4; c++) {
    gemm_bt<4><<<dim3((mcs[c] + 127) / 128, 16), 256, 0, stream>>>(
        yb + (size_t)c0s[c] * 512, ff1t, ff_b1, nullptr, hb, mcs[c], 2048, 512,
        0, 0, 0);
    gemm_bt<5><<<dim3((mcs[c] + 127) / 128, 4), 256, 0, stream>>>(
        hb, ff2t, ff_b2, y + (size_t)c0s[c] * 512, nullptr, mcs[c], 512, 2048,
        0, 0, 0);
  }
  ln_out<<<15600, 256, 0, stream>>>(y, ln2_g, ln2_b, out);
}

// Round 3
// 2150.499 us; speedup vs baseline: 1.1304x; 1.1304x over previous
//
#include <hip/hip_runtime.h>

typedef unsigned short u16;
typedef __attribute__((ext_vector_type(4))) float f32x4;
typedef __attribute__((ext_vector_type(8))) __bf16 bf16x8;
typedef __attribute__((ext_vector_type(4))) unsigned short u16x4;
typedef __attribute__((ext_vector_type(8))) unsigned short u16x8;

#define DEV static __device__ __forceinline__

// ---------------------------------------------------------------------------
// Problem constants: B=16,T=12,NN=325,GP=64,D=512,H=8,HD=64,N_TOT=389
//   BT=192, MG=12288, MP=62400, MKV=74688.
// ---------------------------------------------------------------------------

DEV u16 f2b(float f) {               // fp32 -> bf16 bits, round-to-nearest-even
  union { float f; unsigned u; } c; c.f = f;
  return (u16)((c.u + 0x7FFFu + ((c.u >> 16) & 1u)) >> 16);
}

DEV void async_cp16(void* lds, const void* g) {   // global->LDS, 16B/lane
  __builtin_amdgcn_global_load_lds((__attribute__((address_space(1))) void*)g,
                                   (__attribute__((address_space(3))) void*)lds,
                                   16, 0, 0);
}

// ---------------------------------------------------------------------------
// Weight transpose + bf16 cast:  W(KxN f32) -> Wt(NxK bf16)
// ---------------------------------------------------------------------------
__global__ __launch_bounds__(256) void transpose_w(const float* __restrict__ W,
                                                   u16* __restrict__ Wt,
                                                   int K, int N) {
  __shared__ float t[32][33];
  const int n0 = blockIdx.x * 32, k0 = blockIdx.y * 32;
  const int tx = threadIdx.x, ty = threadIdx.y;
  for (int i = ty; i < 32; i += 8) t[i][tx] = W[(size_t)(k0 + i) * N + n0 + tx];
  __syncthreads();
  for (int i = ty; i < 32; i += 8)
    Wt[(size_t)(n0 + i) * K + k0 + tx] = f2b(t[tx][i]);
}

// ---------------------------------------------------------------------------
// X(f32, [bt][389][512]) -> Xg(bf16 [bt*64][512]) + Xp(bf16 [bt*325][512])
// ---------------------------------------------------------------------------
__global__ __launch_bounds__(256) void convert_x(const float* __restrict__ X,
                                                 u16* __restrict__ Xg,
                                                 u16* __restrict__ Xp) {
  const size_t i = ((size_t)blockIdx.x * 256 + threadIdx.x) * 4;
  const f32x4 v = *(const f32x4*)(X + i);
  const size_t row = i >> 9;
  const int col = (int)(i & 511);
  const int bt = (int)(row / 389), n = (int)(row - (size_t)bt * 389);
  u16x4 w;
#pragma unroll
  for (int u = 0; u < 4; u++) w[u] = f2b(v[u]);
  u16* dst = (n < 64) ? (Xg + (((size_t)bt * 64 + n) << 9) + col)
                      : (Xp + (((size_t)bt * 325 + (n - 64)) << 9) + col);
  *(u16x4*)dst = w;
}

// ---------------------------------------------------------------------------
// GEMM: C = A @ Wt^T + bias.  128x128 tile, 256 thr (4 waves, 2x2 of 64x64),
// BK=64, global_load_lds(16B) staging with inverse-swizzled global source,
// XOR-swizzled ds_read (byte ^= (row&7)<<4) -> conflict-free b128.
// Epilogue MODEs:
//  0: bf16 row-major            1: bf16, row -> bt*389+ofs+rr (x_kv build)
//  2: f32 -> d_out t-rows + bf16 copy   3: f32 row-major
//  4: bf16 + relu               5: f32 accumulate (+=)
//  6: bf16 V^T scatter: [bt][h][d][kv] stride vt_stride
// ---------------------------------------------------------------------------
template <int MODE>
__global__ __launch_bounds__(256) void gemm_bt(
    const u16* __restrict__ A, const u16* __restrict__ Bt,
    const float* __restrict__ bias, float* outF, u16* outB,
    int M, int N, int K, int rows_per, int row_ofs, int vt_stride) {
  __shared__ u16 As[128 * 64];
  __shared__ u16 Bs[128 * 64];
  const int tid = threadIdx.x;
  const int lane = tid & 63, wid = tid >> 6;
  const int l4 = lane >> 4, l16 = lane & 15;
  const int m0 = blockIdx.x * 128, n0 = blockIdx.y * 128;
  const int wr = (wid >> 1) * 64, wc = (wid & 1) * 64;

  // Staging: wave wid covers rows [wid*32, wid*32+32), 4 calls of 8 rows.
  // LDS dest is linear (HW: base + lane*16B); global source column is
  // pre-swizzled so that a swizzled READ returns the logical layout.
  const int srow = lane >> 3;                     // row within 8-row group
  const int scol = 8 * ((lane & 7) ^ srow);       // inverse-swizzled col (elems)
  const u16* gA = A + (size_t)(m0 + wid * 32 + srow) * K + scol;
  const u16* gB = Bt + (size_t)(n0 + wid * 32 + srow) * K + scol;

  f32x4 acc[4][4] = {};

  for (int kk = 0; kk < K; kk += 64) {
    if (kk) __syncthreads();
#pragma unroll
    for (int c = 0; c < 4; c++) {
      async_cp16(As + (wid * 32 + c * 8) * 64, gA + (size_t)(c * 8) * K + kk);
      async_cp16(Bs + (wid * 32 + c * 8) * 64, gB + (size_t)(c * 8) * K + kk);
    }
    __syncthreads();
#pragma unroll
    for (int h = 0; h < 2; h++) {
      // swizzled read offset within a 128B row (in elems)
      const int sw = (((h * 64 + l4 * 16) ^ ((l16 & 7) << 4)) >> 1);
      bf16x8 af[4], bfr[4];
#pragma unroll
      for (int i = 0; i < 4; i++)
        af[i] = *(const bf16x8*)(As + (wr + i * 16 + l16) * 64 + sw);
#pragma unroll
      for (int j = 0; j < 4; j++)
        bfr[j] = *(const bf16x8*)(Bs + (wc + j * 16 + l16) * 64 + sw);
#pragma unroll
      for (int i = 0; i < 4; i++)
#pragma unroll
        for (int j = 0; j < 4; j++)
          acc[i][j] = __builtin_amdgcn_mfma_f32_16x16x32_bf16(af[i], bfr[j],
                                                              acc[i][j], 0, 0, 0);
    }
  }

#pragma unroll
  for (int j = 0; j < 4; j++) {
    const int col = n0 + wc + j * 16 + l16;
    const float bv = bias[col];
#pragma unroll
    for (int i = 0; i < 4; i++) {
#pragma unroll
      for (int r = 0; r < 4; r++) {
        const int row = m0 + wr + i * 16 + l4 * 4 + r;   // C layout: m89/m91
        if (row >= M) continue;
        const float v = acc[i][j][r] + bv;
        if constexpr (MODE == 0) {
          outB[(size_t)row * N + col] = f2b(v);
        } else if constexpr (MODE == 1) {
          const int bt = row / rows_per, rr = row - bt * rows_per;
          outB[((size_t)bt * 389 + row_ofs + rr) * 512 + col] = f2b(v);
        } else if constexpr (MODE == 2) {
          const int bt = row >> 6, rr = row & 63;
          outF[((size_t)bt * 389 + rr) * 512 + col] = v;
          outB[(size_t)row * 512 + col] = f2b(v);
        } else if constexpr (MODE == 3) {
          outF[(size_t)row * N + col] = v;
        } else if constexpr (MODE == 4) {
          outB[(size_t)row * N + col] = f2b(v > 0.f ? v : 0.f);
        } else if constexpr (MODE == 5) {
          outF[(size_t)row * N + col] += v;
        } else {  // MODE 6: V^T
          const int bt = row / rows_per, rr = row - bt * rows_per;
          const int h = col >> 6, d = col & 63;
          outB[(((size_t)bt * 8 + h) * 64 + d) * (size_t)vt_stride +
               (row_ofs + rr)] = f2b(v);
        }
      }
    }
  }
}

// ---------------------------------------------------------------------------
// Fused attention v2: flash-style online softmax, NO inter-wave barriers.
// block=(bt,head), 4 independent waves x 16 q-rows per chunk.
// Per 32-key chunk: S=QK^T (MFMA) -> chunk max (shfl over l16) -> rescale
// o/sum -> exp -> P via tiny per-wave LDS transpose (16x40 u16) -> PV MFMA.
// ---------------------------------------------------------------------------
template <int MQ, int NK, int NKP>
__global__ __launch_bounds__(256, 4) void attn_fused(const u16* __restrict__ Q,
                                                     const u16* __restrict__ Kb,
                                                     const u16* __restrict__ Vt,
                                                     u16* __restrict__ O) {
  constexpr int NCH = NKP / 32;
  constexpr int QC = (MQ + 63) / 64;
  __shared__ __align__(16) u16 Pl[4][16 * 40];   // 5 KB total
  const int tid = threadIdx.x, lane = tid & 63, wid = tid >> 6;
  const int l4 = lane >> 4, l16 = lane & 15;
  const int bt = blockIdx.x >> 3, h = blockIdx.x & 7;
  u16* pw = &Pl[wid][0];
  const u16* vbase = Vt + ((size_t)bt * 8 + h) * 64 * NKP;

  for (int qc = 0; qc < QC; ++qc) {
    const int q0 = qc * 64 + wid * 16;
    if (q0 >= MQ) continue;                       // wave-uniform skip
    const u16* qp = Q + ((size_t)bt * MQ + q0 + l16) * 512 + h * 64 + l4 * 8;
    const bf16x8 aq0 = *(const bf16x8*)qp;
    const bf16x8 aq1 = *(const bf16x8*)(qp + 32);

    f32x4 m, sum, o[4];
#pragma unroll
    for (int r = 0; r < 4; r++) { m[r] = -1e30f; sum[r] = 0.f; }
#pragma unroll
    for (int j = 0; j < 4; j++) o[j] = (f32x4){0.f, 0.f, 0.f, 0.f};

    for (int ch = 0; ch < NCH; ++ch) {
      const int k0 = ch * 32;
      const u16* kp0 = Kb + ((size_t)bt * NK + k0 + l16) * 512 + h * 64 + l4 * 8;
      const u16* kp1 = kp0 + (size_t)16 * 512;
      f32x4 sA = {0.f, 0.f, 0.f, 0.f}, sB = {0.f, 0.f, 0.f, 0.f};
      sA = __builtin_amdgcn_mfma_f32_16x16x32_bf16(aq0, *(const bf16x8*)kp0, sA, 0, 0, 0);
      sA = __builtin_amdgcn_mfma_f32_16x16x32_bf16(aq1, *(const bf16x8*)(kp0 + 32), sA, 0, 0, 0);
      sB = __builtin_amdgcn_mfma_f32_16x16x32_bf16(aq0, *(const bf16x8*)kp1, sB, 0, 0, 0);
      sB = __builtin_amdgcn_mfma_f32_16x16x32_bf16(aq1, *(const bf16x8*)(kp1 + 32), sB, 0, 0, 0);
      const bool vA = (k0 + l16) < NK, vB = (k0 + 16 + l16) < NK;
      f32x4 cm;
#pragma unroll
      for (int r = 0; r < 4; r++) {
        sA[r] = vA ? sA[r] * 0.125f : -1e30f;
        sB[r] = vB ? sB[r] * 0.125f : -1e30f;
        cm[r] = fmaxf(sA[r], sB[r]);
      }
#pragma unroll
      for (int mk = 1; mk < 16; mk <<= 1)
#pragma unroll
        for (int r = 0; r < 4; r++) cm[r] = fmaxf(cm[r], __shfl_xor(cm[r], mk));
      float fr[4];
#pragma unroll
      for (int r = 0; r < 4; r++) {
        const float mn = fmaxf(m[r], cm[r]);
        fr[r] = __expf(m[r] - mn);
        m[r] = mn;
        sA[r] = __expf(sA[r] - mn);
        sB[r] = __expf(sB[r] - mn);
        sum[r] = sum[r] * fr[r] + sA[r] + sB[r];
      }
#pragma unroll
      for (int j = 0; j < 4; j++)
#pragma unroll
        for (int r = 0; r < 4; r++) o[j][r] *= fr[r];
      // P -> per-wave LDS (rows q=l4*4+r stride 40 elems), then A-frag read
#pragma unroll
      for (int r = 0; r < 4; r++) {
        pw[(l4 * 4 + r) * 40 + l16] = f2b(sA[r]);
        pw[(l4 * 4 + r) * 40 + 16 + l16] = f2b(sB[r]);
      }
      asm volatile("s_waitcnt lgkmcnt(0)" ::: "memory");
      const bf16x8 ap = *(const bf16x8*)(pw + l16 * 40 + l4 * 8);
      __builtin_amdgcn_s_setprio(1);
#pragma unroll
      for (int j = 0; j < 4; j++) {
        const bf16x8 bv = *(const bf16x8*)(vbase + (size_t)(j * 16 + l16) * NKP +
                                           k0 + l4 * 8);
        o[j] = __builtin_amdgcn_mfma_f32_16x16x32_bf16(ap, bv, o[j], 0, 0, 0);
      }
      __builtin_amdgcn_s_setprio(0);
    }
    // final sum reduce over l16 group + normalized store
#pragma unroll
    for (int mk = 1; mk < 16; mk <<= 1)
#pragma unroll
      for (int r = 0; r < 4; r++) sum[r] += __shfl_xor(sum[r], mk);
    f32x4 inv;
#pragma unroll
    for (int r = 0; r < 4; r++) inv[r] = 1.f / sum[r];
#pragma unroll
    for (int j = 0; j < 4; j++)
#pragma unroll
      for (int r = 0; r < 4; r++) {
        const int qr = q0 + l4 * 4 + r;
        if (qr < MQ)
          O[((size_t)bt * MQ + qr) * 512 + h * 64 + j * 16 + l16] =
              f2b(o[j][r] * inv[r]);
      }
  }
}

// ---------------------------------------------------------------------------
// LN1: y = LN(X_patch + add) (in-place over add is safe: per-lane RAW only)
// ---------------------------------------------------------------------------
__global__ __launch_bounds__(256) void ln_res(const float* X, const float* add,
                                              const float* g, const float* b,
                                              float* y, u16* yb) {
  const int p = blockIdx.x * 4 + (threadIdx.x >> 6);
  const int lane = threadIdx.x & 63;
  const int bt = p / 325, n = p - bt * 325;
  const float* xr = X + ((size_t)bt * 389 + 64 + n) * 512 + lane * 8;
  const float* ar = add + (size_t)p * 512 + lane * 8;
  float vv[8];
  {
    const f32x4 a0 = *(const f32x4*)xr, a1 = *(const f32x4*)(xr + 4);
    const f32x4 b0 = *(const f32x4*)ar, b1 = *(const f32x4*)(ar + 4);
#pragma unroll
    for (int u = 0; u < 4; u++) {
      vv[u] = a0[u] + b0[u];
      vv[u + 4] = a1[u] + b1[u];
    }
  }
  float s1 = 0.f, s2 = 0.f;
#pragma unroll
  for (int u = 0; u < 8; u++) {
    s1 += vv[u];
    s2 += vv[u] * vv[u];
  }
  for (int m = 1; m < 64; m <<= 1) {
    s1 += __shfl_xor(s1, m);
    s2 += __shfl_xor(s2, m);
  }
  const float mean = s1 * (1.f / 512.f);
  const float inv = rsqrtf(s2 * (1.f / 512.f) - mean * mean + 1e-5f);
  const int c0 = lane * 8;
  f32x4 o0, o1;
  u16x8 ob;
#pragma unroll
  for (int u = 0; u < 8; u++) {
    const float o = (vv[u] - mean) * inv * g[c0 + u] + b[c0 + u];
    if (u < 4) o0[u] = o; else o1[u - 4] = o;
    ob[u] = f2b(o);
  }
  *(f32x4*)(y + (size_t)p * 512 + c0) = o0;
  *(f32x4*)(y + (size_t)p * 512 + c0 + 4) = o1;
  *(u16x8*)(yb + (size_t)p * 512 + c0) = ob;
}

// LN2: d_out patch rows = LN(y)
__global__ __launch_bounds__(256) void ln_out(const float* y, const float* g,
                                              const float* b, float* out) {
  const int p = blockIdx.x * 4 + (threadIdx.x >> 6);
  const int lane = threadIdx.x & 63;
  const int bt = p / 325, n = p - bt * 325;
  const float* yr = y + (size_t)p * 512 + lane * 8;
  float vv[8];
  {
    const f32x4 a0 = *(const f32x4*)yr, a1 = *(const f32x4*)(yr + 4);
#pragma unroll
    for (int u = 0; u < 4; u++) {
      vv[u] = a0[u];
      vv[u + 4] = a1[u];
    }
  }
  float s1 = 0.f, s2 = 0.f;
#pragma unroll
  for (int u = 0; u < 8; u++) {
    s1 += vv[u];
    s2 += vv[u] * vv[u];
  }
  for (int m = 1; m < 64; m <<= 1) {
    s1 += __shfl_xor(s1, m);
    s2 += __shfl_xor(s2, m);
  }
  const float mean = s1 * (1.f / 512.f);
  const float inv = rsqrtf(s2 * (1.f / 512.f) - mean * mean + 1e-5f);
  const int c0 = lane * 8;
  f32x4 o0, o1;
#pragma unroll
  for (int u = 0; u < 8; u++) {
    const float o = (vv[u] - mean) * inv * g[c0 + u] + b[c0 + u];
    if (u < 4) o0[u] = o; else o1[u - 4] = o;
  }
  float* orow = out + ((size_t)bt * 389 + 64 + n) * 512 + c0;
  *(f32x4*)(orow) = o0;
  *(f32x4*)(orow + 4) = o1;
}

// ---------------------------------------------------------------------------
extern "C" void kernel_launch(void* const* d_in, const int* in_sizes, int n_in,
                              void* d_out, int out_size, void* d_ws,
                              size_t ws_size, hipStream_t stream) {
  (void)in_sizes; (void)n_in; (void)out_size; (void)ws_size;
  const float* X = (const float*)d_in[0];
  const float* W[8] = {(const float*)d_in[1],  (const float*)d_in[3],
                       (const float*)d_in[5],  (const float*)d_in[7],
                       (const float*)d_in[9],  (const float*)d_in[11],
                       (const float*)d_in[13], (const float*)d_in[15]};
  const float* Bv[8] = {(const float*)d_in[2],  (const float*)d_in[4],
                        (const float*)d_in[6],  (const float*)d_in[8],
                        (const float*)d_in[10], (const float*)d_in[12],
                        (const float*)d_in[14], (const float*)d_in[16]};
  const float* ff_w1 = (const float*)d_in[17];
  const float* ff_b1 = (const float*)d_in[18];
  const float* ff_w2 = (const float*)d_in[19];
  const float* ff_b2 = (const float*)d_in[20];
  const float* ln1_g = (const float*)d_in[21];
  const float* ln1_b = (const float*)d_in[22];
  const float* ln2_g = (const float*)d_in[23];
  const float* ln2_b = (const float*)d_in[24];
  float* out = (float*)d_out;
  char* ws = (char*)d_ws;

  constexpr size_t MG = 12288, MP = 62400, MKV = 74688, PADR = 128;
  const size_t szQe = (MG + PADR) * 1024;                 // bf16 rows*512*2
  const size_t szKe = (MP + PADR) * 1024;
  const size_t szVte = (size_t)192 * 8 * 64 * 352 * 2;
  const size_t szKd = (MKV + PADR) * 1024;
  const size_t szVtd = (size_t)192 * 8 * 64 * 416 * 2;
  const size_t szY = MP * 2048;                           // f32 62400x512
  const size_t szH = (size_t)(15616 + PADR) * 2048 * 2;

  // Arenas (lifetime-disjoint reuse; peak ~423 MB):
  size_t off = 0;
  const size_t o_wt = off; off += (size_t)4194304 * 2;    // 10 bf16 W^T
  const size_t o_AD = off; off += szY;                    // Xg+Xp, later y
  size_t b1 = szQe + szKe + szVte;                        // enc Q/K/Vt
  size_t b2 = szKe + szKd + szVtd;                        // dec Q/K/Vt
  size_t b3 = szKe + szH;                                 // yb + h
  size_t szB = b1 > b2 ? b1 : b2; if (b3 > szB) szB = b3;
  const size_t o_B = off; off += szB;
  const size_t o_C = off; off += szKe;                    // attn_e+tb | attn_d

  u16* wt = (u16*)(ws + o_wt);
  u16* Xg = (u16*)(ws + o_AD);
  u16* Xp = (u16*)(ws + o_AD + szQe);
  float* y = (float*)(ws + o_AD);
  u16* Qe = (u16*)(ws + o_B);
  u16* Ke = (u16*)(ws + o_B + szQe);
  u16* Vte = (u16*)(ws + o_B + szQe + szKe);
  u16* Qd = (u16*)(ws + o_B);
  u16* Kd = (u16*)(ws + o_B + szKe);
  u16* Vtd = (u16*)(ws + o_B + szKe + szKd);
  u16* yb = (u16*)(ws + o_B);
  u16* hb = (u16*)(ws + o_B + szKe);
  u16* attn_e = (u16*)(ws + o_C);
  u16* tb = (u16*)(ws + o_C + szQe);
  u16* attn_d = (u16*)(ws + o_C);

  u16* wt_p[8];
  for (int i = 0; i < 8; i++) wt_p[i] = wt + (size_t)i * 262144;
  u16* ff1t = wt + (size_t)8 * 262144;
  u16* ff2t = ff1t + (size_t)1048576;

  dim3 tblk(32, 8);
  for (int i = 0; i < 8; i++)
    transpose_w<<<dim3(16, 16), tblk, 0, stream>>>(W[i], wt_p[i], 512, 512);
  transpose_w<<<dim3(64, 16), tblk, 0, stream>>>(ff_w1, ff1t, 512, 2048);
  transpose_w<<<dim3(16, 64), tblk, 0, stream>>>(ff_w2, ff2t, 2048, 512);

  convert_x<<<37344, 256, 0, stream>>>(X, Xg, Xp);

  // Encoder
  gemm_bt<0><<<dim3(96, 4), 256, 0, stream>>>(Xg, wt_p[0], Bv[0], nullptr, Qe,
                                              (int)MG, 512, 512, 0, 0, 0);
  gemm_bt<0><<<dim3(488, 4), 256, 0, stream>>>(Xp, wt_p[1], Bv[1], nullptr, Ke,
                                               (int)MP, 512, 512, 0, 0, 0);
  gemm_bt<6><<<dim3(488, 4), 256, 0, stream>>>(Xp, wt_p[2], Bv[2], nullptr, Vte,
                                               (int)MP, 512, 512, 325, 0, 352);
  attn_fused<64, 325, 352><<<1536, 256, 0, stream>>>(Qe, Ke, Vte, attn_e);
  gemm_bt<2><<<dim3(96, 4), 256, 0, stream>>>(attn_e, wt_p[3], Bv[3], out, tb,
                                              (int)MG, 512, 512, 0, 0, 0);

  // Decoder (x_kv = [t ; patch] built via row-remap epilogues)
  gemm_bt<0><<<dim3(488, 4), 256, 0, stream>>>(Xp, wt_p[4], Bv[4], nullptr, Qd,
                                               (int)MP, 512, 512, 0, 0, 0);
  gemm_bt<1><<<dim3(96, 4), 256, 0, stream>>>(tb, wt_p[5], Bv[5], nullptr, Kd,
                                              (int)MG, 512, 512, 64, 0, 0);
  gemm_bt<1><<<dim3(488, 4), 256, 0, stream>>>(Xp, wt_p[5], Bv[5], nullptr, Kd,
                                               (int)MP, 512, 512, 325, 64, 0);
  gemm_bt<6><<<dim3(96, 4), 256, 0, stream>>>(tb, wt_p[6], Bv[6], nullptr, Vtd,
                                              (int)MG, 512, 512, 64, 0, 416);
  gemm_bt<6><<<dim3(488, 4), 256, 0, stream>>>(Xp, wt_p[6], Bv[6], nullptr, Vtd,
                                               (int)MP, 512, 512, 325, 64, 416);
  attn_fused<325, 389, 416><<<1536, 256, 0, stream>>>(Qd, Kd, Vtd, attn_d);
  gemm_bt<3><<<dim3(488, 4), 256, 0, stream>>>(attn_d, wt_p[7], Bv[7], y,
                                               nullptr, (int)MP, 512, 512, 0, 0,
                                               0);

  // LN1 (residual with original fp32 patch), then FF chunked x4, then LN2.
  ln_res<<<15600, 256, 0, stream>>>(X, y, ln1_g, ln1_b, y, yb);

  const int c0s[4] = {0, 15616, 31232, 46848};
  const int mcs[4] = {15616, 15616, 15616, 15552};
  for (int c = 0; c < 4; c++) {
    gemm_bt<4><<<dim3((mcs[c] + 127) / 128, 16), 256, 0, stream>>>(
        yb + (size_t)c0s[c] * 512, ff1t, ff_b1, nullptr, hb, mcs[c], 2048, 512,
        0, 0, 0);
    gemm_bt<5><<<dim3((mcs[c] + 127) / 128, 4), 256, 0, stream>>>(
        hb, ff2t, ff_b2, y + (size_t)c0s[c] * 512, nullptr, mcs[c], 512, 2048,
        0, 0, 0);
  }
  ln_out<<<15600, 256, 0, stream>>>(y, ln2_g, ln2_b, out);
}

// Round 4
// 2048.340 us; speedup vs baseline: 1.1867x; 1.0499x over previous
//
#include <hip/hip_runtime.h>

typedef unsigned short u16;
typedef __attribute__((ext_vector_type(4))) float f32x4;
typedef __attribute__((ext_vector_type(8))) __bf16 bf16x8;
typedef __attribute__((ext_vector_type(4))) unsigned short u16x4;
typedef __attribute__((ext_vector_type(8))) unsigned short u16x8;

#define DEV static __device__ __forceinline__
#define MFMA_B16 __builtin_amdgcn_mfma_f32_16x16x32_bf16

// ---------------------------------------------------------------------------
// B=16,T=12,NN=325,GP=64,D=512,H=8,HD=64,N_TOT=389; BT=192.
// Patch rows padded to RP=328/bt (mult of 8; 192*328=62976=492*128 exact).
//   MG=12288 glob rows, MPp=62976 padded patch rows, MKV=74688 x_kv rows.
// ---------------------------------------------------------------------------

DEV u16 f2b(float f) {               // fp32 -> bf16, round-to-nearest-even
  union { float f; unsigned u; } c; c.f = f;
  return (u16)((c.u + 0x7FFFu + ((c.u >> 16) & 1u)) >> 16);
}

DEV void async_cp16(void* lds, const void* g) {   // global->LDS, 16B/lane
  __builtin_amdgcn_global_load_lds((__attribute__((address_space(1))) void*)g,
                                   (__attribute__((address_space(3))) void*)lds,
                                   16, 0, 0);
}

// ---------------------------------------------------------------------------
__global__ __launch_bounds__(256) void transpose_w(const float* __restrict__ W,
                                                   u16* __restrict__ Wt,
                                                   int K, int N) {
  __shared__ float t[32][33];
  const int n0 = blockIdx.x * 32, k0 = blockIdx.y * 32;
  const int tx = threadIdx.x, ty = threadIdx.y;
  for (int i = ty; i < 32; i += 8) t[i][tx] = W[(size_t)(k0 + i) * N + n0 + tx];
  __syncthreads();
  for (int i = ty; i < 32; i += 8)
    Wt[(size_t)(n0 + i) * K + k0 + tx] = f2b(t[tx][i]);
}

// X(f32 [bt][389][512]) -> Xg(bf16 [bt*64][512]) + Xp(bf16 [bt*328(pad)][512])
__global__ __launch_bounds__(256) void convert_x(const float* __restrict__ X,
                                                 u16* __restrict__ Xg,
                                                 u16* __restrict__ Xp) {
  const size_t i = ((size_t)blockIdx.x * 256 + threadIdx.x) * 4;
  const f32x4 v = *(const f32x4*)(X + i);
  const size_t row = i >> 9;
  const int col = (int)(i & 511);
  const int bt = (int)(row / 389), n = (int)(row - (size_t)bt * 389);
  u16x4 w;
#pragma unroll
  for (int u = 0; u < 4; u++) w[u] = f2b(v[u]);
  u16* dst = (n < 64) ? (Xg + (((size_t)bt * 64 + n) << 9) + col)
                      : (Xp + (((size_t)bt * 328 + (n - 64)) << 9) + col);
  *(u16x4*)dst = w;
}

// ---------------------------------------------------------------------------
// GEMM: C = A @ Wt^T + bias. 128x128 tile, 4 waves (2x2 of 64x64), BK=64,
// global_load_lds(16B) with inverse-swizzled source + XOR-swizzled ds_read.
// Grid: blockIdx.x = N-panel (fast -> B panel L2-resident, A streamed once),
//       blockIdx.y = M-block.
// MODEs: 0 bf16 row-major | 1 bf16 row->bt*389+ofs+rr, skip rr>=aux
//        2 f32 d_out t-rows + bf16 copy | 3 f32 row-major | 4 bf16+relu
//        5 f32 += | 6 bf16 V^T [bt][h][d][kv] stride aux, LDS-staged transpose
// ---------------------------------------------------------------------------
template <int MODE>
__global__ __launch_bounds__(256) void gemm_bt(
    const u16* __restrict__ A, const u16* __restrict__ Bt,
    const float* __restrict__ bias, float* outF, u16* outB,
    int M, int N, int K, int rows_per, int row_ofs, int aux) {
  __shared__ u16 SH[2][128 * 64];
  u16* As = &SH[0][0];
  u16* Bs = &SH[1][0];
  const int tid = threadIdx.x;
  const int lane = tid & 63, wid = tid >> 6;
  const int l4 = lane >> 4, l16 = lane & 15;
  const int n0 = blockIdx.x * 128, m0 = blockIdx.y * 128;
  const int wr = (wid >> 1) * 64, wc = (wid & 1) * 64;

  const int srow = lane >> 3;                  // row within 8-row group
  const int scol = 8 * ((lane & 7) ^ srow);    // inverse-swizzled col (elems)
  const u16* gA = A + (size_t)(m0 + wid * 32 + srow) * K + scol;
  const u16* gB = Bt + (size_t)(n0 + wid * 32 + srow) * K + scol;

  f32x4 acc[4][4] = {};

  for (int kk = 0; kk < K; kk += 64) {
    if (kk) __syncthreads();
#pragma unroll
    for (int c = 0; c < 4; c++) {
      async_cp16(As + (wid * 32 + c * 8) * 64, gA + (size_t)(c * 8) * K + kk);
      async_cp16(Bs + (wid * 32 + c * 8) * 64, gB + (size_t)(c * 8) * K + kk);
    }
    __syncthreads();
#pragma unroll
    for (int hh = 0; hh < 2; hh++) {
      const int sw = (((hh * 64 + l4 * 16) ^ ((l16 & 7) << 4)) >> 1);
      bf16x8 af[4], bfr[4];
#pragma unroll
      for (int i = 0; i < 4; i++)
        af[i] = *(const bf16x8*)(As + (wr + i * 16 + l16) * 64 + sw);
#pragma unroll
      for (int j = 0; j < 4; j++)
        bfr[j] = *(const bf16x8*)(Bs + (wc + j * 16 + l16) * 64 + sw);
#pragma unroll
      for (int i = 0; i < 4; i++)
#pragma unroll
        for (int j = 0; j < 4; j++)
          acc[i][j] = MFMA_B16(af[i], bfr[j], acc[i][j], 0, 0, 0);
    }
  }

  if constexpr (MODE == 6) {
    // Stage C in LDS, then write V^T with aligned 16B stores.
    // Requires rows_per % 8 == 0 (rows_per in {64,328}).
    __syncthreads();
    u16* cs = &SH[0][0];                       // 128x128 u16 = 32KB
#pragma unroll
    for (int j = 0; j < 4; j++) {
      const float bv = bias[n0 + wc + j * 16 + l16];
#pragma unroll
      for (int i = 0; i < 4; i++)
#pragma unroll
        for (int r = 0; r < 4; r++)
          cs[(wr + i * 16 + l4 * 4 + r) * 128 + wc + j * 16 + l16] =
              f2b(acc[i][j][r] + bv);
    }
    __syncthreads();
    const int c = tid & 127;
    const int kvh = (tid >> 7) * 64;
    const int gh = (n0 + c) >> 6, gd = (n0 + c) & 63;
#pragma unroll
    for (int g = 0; g < 8; g++) {
      const int row0 = m0 + kvh + g * 8;
      if (row0 >= M) break;
      const int bt0 = row0 / rows_per;
      const int rr = row0 - bt0 * rows_per;    // multiple of 8
      u16x8 w;
#pragma unroll
      for (int e = 0; e < 8; e++) w[e] = cs[(kvh + g * 8 + e) * 128 + c];
      *(u16x8*)(outB + (((size_t)bt0 * 8 + gh) * 64 + gd) * (size_t)aux +
                row_ofs + rr) = w;
    }
  } else {
#pragma unroll
    for (int j = 0; j < 4; j++) {
      const int col = n0 + wc + j * 16 + l16;
      const float bv = bias[col];
#pragma unroll
      for (int i = 0; i < 4; i++) {
#pragma unroll
        for (int r = 0; r < 4; r++) {
          const int row = m0 + wr + i * 16 + l4 * 4 + r;   // C layout m89/m91
          if (row >= M) continue;
          const float v = acc[i][j][r] + bv;
          if constexpr (MODE == 0) {
            outB[(size_t)row * N + col] = f2b(v);
          } else if constexpr (MODE == 1) {
            const int bt = row / rows_per, rr = row - bt * rows_per;
            if (rr < aux)
              outB[((size_t)bt * 389 + row_ofs + rr) * 512 + col] = f2b(v);
          } else if constexpr (MODE == 2) {
            const int bt = row >> 6, rr = row & 63;
            outF[((size_t)bt * 389 + rr) * 512 + col] = v;
            outB[(size_t)row * 512 + col] = f2b(v);
          } else if constexpr (MODE == 3) {
            outF[(size_t)row * N + col] = v;
          } else if constexpr (MODE == 4) {
            outB[(size_t)row * N + col] = f2b(v > 0.f ? v : 0.f);
          } else {  // 5
            outF[(size_t)row * N + col] += v;
          }
        }
      }
    }
  }
}

// ---------------------------------------------------------------------------
// Fused attention v3: flash online softmax, no inter-wave barriers.
// block=(bt,head); 4 waves; T2: 2 q-tiles (32 q rows) per wave per pass.
// 64-key chunks: K-frags loaded once, shared by both q-tiles; exact
// defer-max (skip rescale when no lane grew). P via per-wave LDS transpose.
// QS/KS = per-bt row strides of Q/K buffers; NK = valid keys; NKP = padded.
// ---------------------------------------------------------------------------
template <int QS, int MQ, int KS, int NK, int NKP, bool T2>
__global__ __launch_bounds__(256) void attn_fused(
    const u16* __restrict__ Q, const u16* __restrict__ Kb,
    const u16* __restrict__ Vt, u16* __restrict__ O) {
  constexpr int NCH = NKP / 64;
  constexpr int QTW = T2 ? 128 : 64;
  constexpr int QP = (MQ + QTW - 1) / QTW;
  constexpr int PSTR = 72;
  __shared__ __align__(16) u16 Pl[4][2][16 * PSTR];   // 18KB
  const int tid = threadIdx.x, lane = tid & 63, wid = tid >> 6;
  const int l4 = lane >> 4, l16 = lane & 15;
  const int bt = blockIdx.x >> 3, h = blockIdx.x & 7;
  u16* pw0 = &Pl[wid][0][0];
  u16* pw1 = &Pl[wid][1][0];
  const u16* vb = Vt + ((size_t)bt * 8 + h) * (size_t)(64 * NKP);
  const u16* qb = Q + (size_t)bt * QS * 512 + h * 64;
  const u16* kb = Kb + (size_t)bt * KS * 512 + h * 64;

  for (int qp = 0; qp < QP; ++qp) {
    const int q0 = qp * QTW + wid * 16;
    const bool bL = T2 && (q0 + 64 < MQ);      // tile-B live (wave-uniform)
    const u16* qpA = qb + (size_t)(q0 + l16) * 512 + l4 * 8;
    const bf16x8 aq0A = *(const bf16x8*)qpA;
    const bf16x8 aq1A = *(const bf16x8*)(qpA + 32);
    bf16x8 aq0B, aq1B;
    if (bL) {
      aq0B = *(const bf16x8*)(qpA + 32768);
      aq1B = *(const bf16x8*)(qpA + 32768 + 32);
    }

    f32x4 m0v, m1v, sum0, sum1, o0[4], o1[4];
#pragma unroll
    for (int r = 0; r < 4; r++) {
      m0v[r] = -1e30f; m1v[r] = -1e30f; sum0[r] = 0.f; sum1[r] = 0.f;
    }
#pragma unroll
    for (int j = 0; j < 4; j++) {
      o0[j] = (f32x4){0.f, 0.f, 0.f, 0.f};
      o1[j] = (f32x4){0.f, 0.f, 0.f, 0.f};
    }

    for (int ch = 0; ch < NCH; ++ch) {
      const int k0 = ch * 64;
      f32x4 sc0[4], sc1[4];
#pragma unroll
      for (int s = 0; s < 4; s++) {
        const u16* kp = kb + (size_t)(k0 + s * 16 + l16) * 512 + l4 * 8;
        const bf16x8 kf0 = *(const bf16x8*)kp;
        const bf16x8 kf1 = *(const bf16x8*)(kp + 32);
        f32x4 a = (f32x4){0.f, 0.f, 0.f, 0.f};
        a = MFMA_B16(aq0A, kf0, a, 0, 0, 0);
        a = MFMA_B16(aq1A, kf1, a, 0, 0, 0);
        sc0[s] = a;
        if (bL) {
          f32x4 bacc = (f32x4){0.f, 0.f, 0.f, 0.f};
          bacc = MFMA_B16(aq0B, kf0, bacc, 0, 0, 0);
          bacc = MFMA_B16(aq1B, kf1, bacc, 0, 0, 0);
          sc1[s] = bacc;
        }
      }
      // scale + mask (col = k = l16-group)
#pragma unroll
      for (int s = 0; s < 4; s++) {
        const bool vld = (k0 + s * 16 + l16) < NK;
#pragma unroll
        for (int r = 0; r < 4; r++) {
          sc0[s][r] = vld ? sc0[s][r] * 0.125f : -1e30f;
          if (bL) sc1[s][r] = vld ? sc1[s][r] * 0.125f : -1e30f;
        }
      }
      f32x4 c0, c1;
#pragma unroll
      for (int r = 0; r < 4; r++) {
        c0[r] = fmaxf(fmaxf(sc0[0][r], sc0[1][r]), fmaxf(sc0[2][r], sc0[3][r]));
        if (bL)
          c1[r] = fmaxf(fmaxf(sc1[0][r], sc1[1][r]), fmaxf(sc1[2][r], sc1[3][r]));
      }
#pragma unroll
      for (int mk = 1; mk < 16; mk <<= 1)
#pragma unroll
        for (int r = 0; r < 4; r++) {
          c0[r] = fmaxf(c0[r], __shfl_xor(c0[r], mk));
          if (bL) c1[r] = fmaxf(c1[r], __shfl_xor(c1[r], mk));
        }
      // exact defer-max: rescale only if some lane's max grew
      float g = c0[0] - m0v[0];
#pragma unroll
      for (int r = 1; r < 4; r++) g = fmaxf(g, c0[r] - m0v[r]);
      if (bL)
#pragma unroll
        for (int r = 0; r < 4; r++) g = fmaxf(g, c1[r] - m1v[r]);
      if (__any(g > 0.f)) {
#pragma unroll
        for (int r = 0; r < 4; r++) {
          float mn = fmaxf(m0v[r], c0[r]);
          float f = __expf(m0v[r] - mn);
          m0v[r] = mn; sum0[r] *= f;
#pragma unroll
          for (int j = 0; j < 4; j++) o0[j][r] *= f;
          if (bL) {
            mn = fmaxf(m1v[r], c1[r]); f = __expf(m1v[r] - mn);
            m1v[r] = mn; sum1[r] *= f;
#pragma unroll
            for (int j = 0; j < 4; j++) o1[j][r] *= f;
          }
        }
      }
      // exp, partial sums, P -> LDS transpose buffers
#pragma unroll
      for (int s = 0; s < 4; s++)
#pragma unroll
        for (int r = 0; r < 4; r++) {
          const float e0 = __expf(sc0[s][r] - m0v[r]);
          sum0[r] += e0;
          pw0[(l4 * 4 + r) * PSTR + s * 16 + l16] = f2b(e0);
          if (bL) {
            const float e1 = __expf(sc1[s][r] - m1v[r]);
            sum1[r] += e1;
            pw1[(l4 * 4 + r) * PSTR + s * 16 + l16] = f2b(e1);
          }
        }
      asm volatile("s_waitcnt lgkmcnt(0)" ::: "memory");
      const bf16x8 apA0 = *(const bf16x8*)(pw0 + l16 * PSTR + l4 * 8);
      const bf16x8 apA1 = *(const bf16x8*)(pw0 + l16 * PSTR + 32 + l4 * 8);
      bf16x8 apB0, apB1;
      if (bL) {
        apB0 = *(const bf16x8*)(pw1 + l16 * PSTR + l4 * 8);
        apB1 = *(const bf16x8*)(pw1 + l16 * PSTR + 32 + l4 * 8);
      }
      __builtin_amdgcn_s_setprio(1);
#pragma unroll
      for (int j = 0; j < 4; j++) {
        const u16* vp = vb + (size_t)(j * 16 + l16) * NKP + k0 + l4 * 8;
        const bf16x8 v0 = *(const bf16x8*)vp;
        const bf16x8 v1 = *(const bf16x8*)(vp + 32);
        o0[j] = MFMA_B16(apA0, v0, o0[j], 0, 0, 0);
        o0[j] = MFMA_B16(apA1, v1, o0[j], 0, 0, 0);
        if (bL) {
          o1[j] = MFMA_B16(apB0, v0, o1[j], 0, 0, 0);
          o1[j] = MFMA_B16(apB1, v1, o1[j], 0, 0, 0);
        }
      }
      __builtin_amdgcn_s_setprio(0);
    }
    // final k-sum reduce + normalized store
#pragma unroll
    for (int mk = 1; mk < 16; mk <<= 1)
#pragma unroll
      for (int r = 0; r < 4; r++) {
        sum0[r] += __shfl_xor(sum0[r], mk);
        if (bL) sum1[r] += __shfl_xor(sum1[r], mk);
      }
#pragma unroll
    for (int j = 0; j < 4; j++)
#pragma unroll
      for (int r = 0; r < 4; r++) {
        const int qr = q0 + l4 * 4 + r;
        if (qr < MQ)
          O[((size_t)bt * QS + qr) * 512 + h * 64 + j * 16 + l16] =
              f2b(o0[j][r] / sum0[r]);
        if (bL && qr + 64 < MQ)
          O[((size_t)bt * QS + qr + 64) * 512 + h * 64 + j * 16 + l16] =
              f2b(o1[j][r] / sum1[r]);
      }
  }
}

// ---------------------------------------------------------------------------
// LN1: y = LN(X_patch + y), y padded [bt*328+n]; also bf16 copy yb.
__global__ __launch_bounds__(256) void ln_res(const float* __restrict__ X,
                                              float* __restrict__ y,
                                              const float* g, const float* b,
                                              u16* __restrict__ yb) {
  const int p = blockIdx.x * 4 + (threadIdx.x >> 6);
  const int lane = threadIdx.x & 63;
  const int bt = p / 325, n = p - bt * 325;
  const size_t yrow = ((size_t)bt * 328 + n) * 512;
  const float* xr = X + ((size_t)bt * 389 + 64 + n) * 512 + lane * 8;
  const float* ar = y + yrow + lane * 8;
  float vv[8];
  {
    const f32x4 a0 = *(const f32x4*)xr, a1 = *(const f32x4*)(xr + 4);
    const f32x4 b0 = *(const f32x4*)ar, b1 = *(const f32x4*)(ar + 4);
#pragma unroll
    for (int u = 0; u < 4; u++) { vv[u] = a0[u] + b0[u]; vv[u + 4] = a1[u] + b1[u]; }
  }
  float s1 = 0.f, s2 = 0.f;
#pragma unroll
  for (int u = 0; u < 8; u++) { s1 += vv[u]; s2 += vv[u] * vv[u]; }
  for (int m = 1; m < 64; m <<= 1) { s1 += __shfl_xor(s1, m); s2 += __shfl_xor(s2, m); }
  const float mean = s1 * (1.f / 512.f);
  const float inv = rsqrtf(s2 * (1.f / 512.f) - mean * mean + 1e-5f);
  const int c0 = lane * 8;
  f32x4 o0, o1;
  u16x8 ob;
#pragma unroll
  for (int u = 0; u < 8; u++) {
    const float o = (vv[u] - mean) * inv * g[c0 + u] + b[c0 + u];
    if (u < 4) o0[u] = o; else o1[u - 4] = o;
    ob[u] = f2b(o);
  }
  *(f32x4*)(y + yrow + c0) = o0;
  *(f32x4*)(y + yrow + c0 + 4) = o1;
  *(u16x8*)(yb + yrow + c0) = ob;
}

// LN2: d_out patch rows = LN(y)
__global__ __launch_bounds__(256) void ln_out(const float* __restrict__ y,
                                              const float* g, const float* b,
                                              float* __restrict__ out) {
  const int p = blockIdx.x * 4 + (threadIdx.x >> 6);
  const int lane = threadIdx.x & 63;
  const int bt = p / 325, n = p - bt * 325;
  const float* yr = y + ((size_t)bt * 328 + n) * 512 + lane * 8;
  float vv[8];
  {
    const f32x4 a0 = *(const f32x4*)yr, a1 = *(const f32x4*)(yr + 4);
#pragma unroll
    for (int u = 0; u < 4; u++) { vv[u] = a0[u]; vv[u + 4] = a1[u]; }
  }
  float s1 = 0.f, s2 = 0.f;
#pragma unroll
  for (int u = 0; u < 8; u++) { s1 += vv[u]; s2 += vv[u] * vv[u]; }
  for (int m = 1; m < 64; m <<= 1) { s1 += __shfl_xor(s1, m); s2 += __shfl_xor(s2, m); }
  const float mean = s1 * (1.f / 512.f);
  const float inv = rsqrtf(s2 * (1.f / 512.f) - mean * mean + 1e-5f);
  const int c0 = lane * 8;
  f32x4 o0, o1;
#pragma unroll
  for (int u = 0; u < 8; u++) {
    const float o = (vv[u] - mean) * inv * g[c0 + u] + b[c0 + u];
    if (u < 4) o0[u] = o; else o1[u - 4] = o;
  }
  float* orow = out + ((size_t)bt * 389 + 64 + n) * 512 + c0;
  *(f32x4*)(orow) = o0;
  *(f32x4*)(orow + 4) = o1;
}

// ---------------------------------------------------------------------------
extern "C" void kernel_launch(void* const* d_in, const int* in_sizes, int n_in,
                              void* d_out, int out_size, void* d_ws,
                              size_t ws_size, hipStream_t stream) {
  (void)in_sizes; (void)n_in; (void)out_size; (void)ws_size;
  const float* X = (const float*)d_in[0];
  const float* W[8] = {(const float*)d_in[1],  (const float*)d_in[3],
                       (const float*)d_in[5],  (const float*)d_in[7],
                       (const float*)d_in[9],  (const float*)d_in[11],
                       (const float*)d_in[13], (const float*)d_in[15]};
  const float* Bv[8] = {(const float*)d_in[2],  (const float*)d_in[4],
                        (const float*)d_in[6],  (const float*)d_in[8],
                        (const float*)d_in[10], (const float*)d_in[12],
                        (const float*)d_in[14], (const float*)d_in[16]};
  const float* ff_w1 = (const float*)d_in[17];
  const float* ff_b1 = (const float*)d_in[18];
  const float* ff_w2 = (const float*)d_in[19];
  const float* ff_b2 = (const float*)d_in[20];
  const float* ln1_g = (const float*)d_in[21];
  const float* ln1_b = (const float*)d_in[22];
  const float* ln2_g = (const float*)d_in[23];
  const float* ln2_b = (const float*)d_in[24];
  float* out = (float*)d_out;
  char* ws = (char*)d_ws;

  // Sizes (bytes). Patch rows padded to 328/bt; +128-row staging pads.
  constexpr size_t szW   = 8388608;                      // 10 bf16 W^T
  constexpr size_t szXp  = (size_t)(62976 + 128) * 1024; // 64.6MB (also yb)
  constexpr size_t szQe  = (size_t)(12288 + 128) * 1024; // 12.7MB
  constexpr size_t szKe  = szXp;
  constexpr size_t szVte = (size_t)192 * 8 * 64 * 384 * 2;  // 75.5MB
  constexpr size_t szKd  = (size_t)(74688 + 128) * 1024;    // 76.6MB
  constexpr size_t szVtd = (size_t)192 * 8 * 64 * 448 * 2;  // 88.1MB
  // Regions (lifetime-disjoint): total ~404MB
  constexpr size_t o1 = szW;                  // Xp -> yb
  constexpr size_t o2 = o1 + szXp;            // Xg -> attn_e
  constexpr size_t o3 = o2 + szQe;            // tb
  constexpr size_t o4 = o3 + szQe;            // {Qe,Ke,Vte} -> {Qd,Kd} -> y
  constexpr size_t o5 = o4 + szQe + szKe + szVte;  // Vtd -> hb
  constexpr size_t o6 = o5 + szVtd;           // attn_d

  u16* wt     = (u16*)(ws);
  u16* Xp     = (u16*)(ws + o1);
  u16* yb     = (u16*)(ws + o1);
  u16* Xg     = (u16*)(ws + o2);
  u16* attn_e = (u16*)(ws + o2);
  u16* tb     = (u16*)(ws + o3);
  u16* Qe     = (u16*)(ws + o4);
  u16* Ke     = (u16*)(ws + o4 + szQe);
  u16* Vte    = (u16*)(ws + o4 + szQe + szKe);
  u16* Qd     = (u16*)(ws + o4);
  u16* Kd     = (u16*)(ws + o4 + szXp);
  float* y    = (float*)(ws + o4);
  u16* Vtd    = (u16*)(ws + o5);
  u16* hb     = (u16*)(ws + o5);
  u16* attn_d = (u16*)(ws + o6);

  u16* wt_p[8];
  for (int i = 0; i < 8; i++) wt_p[i] = wt + (size_t)i * 262144;
  u16* ff1t = wt + (size_t)8 * 262144;
  u16* ff2t = ff1t + (size_t)1048576;

  dim3 tblk(32, 8);
  for (int i = 0; i < 8; i++)
    transpose_w<<<dim3(16, 16), tblk, 0, stream>>>(W[i], wt_p[i], 512, 512);
  transpose_w<<<dim3(64, 16), tblk, 0, stream>>>(ff_w1, ff1t, 512, 2048);
  transpose_w<<<dim3(16, 64), tblk, 0, stream>>>(ff_w2, ff2t, 2048, 512);

  convert_x<<<37344, 256, 0, stream>>>(X, Xg, Xp);

  // Encoder: t = MHA(glob -> patch)
  gemm_bt<0><<<dim3(4, 96), 256, 0, stream>>>(Xg, wt_p[0], Bv[0], nullptr, Qe,
                                              12288, 512, 512, 0, 0, 0);
  gemm_bt<0><<<dim3(4, 492), 256, 0, stream>>>(Xp, wt_p[1], Bv[1], nullptr, Ke,
                                               62976, 512, 512, 0, 0, 0);
  gemm_bt<6><<<dim3(4, 492), 256, 0, stream>>>(Xp, wt_p[2], Bv[2], nullptr, Vte,
                                               62976, 512, 512, 328, 0, 384);
  attn_fused<64, 64, 328, 325, 384, false><<<1536, 256, 0, stream>>>(
      Qe, Ke, Vte, attn_e);
  gemm_bt<2><<<dim3(4, 96), 256, 0, stream>>>(attn_e, wt_p[3], Bv[3], out, tb,
                                              12288, 512, 512, 0, 0, 0);

  // Decoder: x_kv = [t ; patch] via row-remap epilogues
  gemm_bt<0><<<dim3(4, 492), 256, 0, stream>>>(Xp, wt_p[4], Bv[4], nullptr, Qd,
                                               62976, 512, 512, 0, 0, 0);
  gemm_bt<1><<<dim3(4, 96), 256, 0, stream>>>(tb, wt_p[5], Bv[5], nullptr, Kd,
                                              12288, 512, 512, 64, 0, 64);
  gemm_bt<1><<<dim3(4, 492), 256, 0, stream>>>(Xp, wt_p[5], Bv[5], nullptr, Kd,
                                               62976, 512, 512, 328, 64, 325);
  gemm_bt<6><<<dim3(4, 96), 256, 0, stream>>>(tb, wt_p[6], Bv[6], nullptr, Vtd,
                                              12288, 512, 512, 64, 0, 448);
  gemm_bt<6><<<dim3(4, 492), 256, 0, stream>>>(Xp, wt_p[6], Bv[6], nullptr, Vtd,
                                               62976, 512, 512, 328, 64, 448);
  attn_fused<328, 325, 389, 389, 448, true><<<1536, 256, 0, stream>>>(
      Qd, Kd, Vtd, attn_d);
  gemm_bt<3><<<dim3(4, 492), 256, 0, stream>>>(attn_d, wt_p[7], Bv[7], y,
                                               nullptr, 62976, 512, 512, 0, 0, 0);

  // LN1 (+residual), FF (4 row-chunks of 15744 = 123*128), LN2.
  ln_res<<<15600, 256, 0, stream>>>(X, y, ln1_g, ln1_b, yb);

  for (int c = 0; c < 4; c++) {
    const size_t ro = (size_t)c * 15744;
    gemm_bt<4><<<dim3(16, 123), 256, 0, stream>>>(
        yb + ro * 512, ff1t, ff_b1, nullptr, hb, 15744, 2048, 512, 0, 0, 0);
    gemm_bt<5><<<dim3(4, 123), 256, 0, stream>>>(
        hb, ff2t, ff_b2, y + ro * 512, nullptr, 15744, 512, 2048, 0, 0, 0);
  }
  ln_out<<<15600, 256, 0, stream>>>(y, ln2_g, ln2_b, out);
}

// Round 5
// 1895.705 us; speedup vs baseline: 1.2823x; 1.0805x over previous
//
#include <hip/hip_runtime.h>

typedef unsigned short u16;
typedef __attribute__((ext_vector_type(4))) float f32x4;
typedef __attribute__((ext_vector_type(8))) __bf16 bf16x8;
typedef __attribute__((ext_vector_type(4))) unsigned short u16x4;
typedef __attribute__((ext_vector_type(8))) unsigned short u16x8;

#define DEV static __device__ __forceinline__
#define MFMA_B16 __builtin_amdgcn_mfma_f32_16x16x32_bf16

// ---------------------------------------------------------------------------
// B=16,T=12,NN=325,GP=64,D=512,H=8,HD=64,N_TOT=389; BT=192.
// Patch rows padded to RP=328/bt (mult of 8; 192*328=62976=492*128 exact).
// ---------------------------------------------------------------------------

DEV u16 f2b(float f) {               // fp32 -> bf16, round-to-nearest-even
  union { float f; unsigned u; } c; c.f = f;
  return (u16)((c.u + 0x7FFFu + ((c.u >> 16) & 1u)) >> 16);
}

DEV float ex2(float x) {             // 2^x, single v_exp_f32
  float r; asm("v_exp_f32 %0, %1" : "=v"(r) : "v"(x)); return r;
}

DEV void async_cp16(void* lds, const void* g) {   // global->LDS, 16B/lane
  __builtin_amdgcn_global_load_lds((__attribute__((address_space(1))) void*)g,
                                   (__attribute__((address_space(3))) void*)lds,
                                   16, 0, 0);
}

template <bool B> struct bc { static constexpr bool value = B; };

// ---------------------------------------------------------------------------
__global__ __launch_bounds__(256) void transpose_w(const float* __restrict__ W,
                                                   u16* __restrict__ Wt,
                                                   int K, int N) {
  __shared__ float t[32][33];
  const int n0 = blockIdx.x * 32, k0 = blockIdx.y * 32;
  const int tx = threadIdx.x, ty = threadIdx.y;
  for (int i = ty; i < 32; i += 8) t[i][tx] = W[(size_t)(k0 + i) * N + n0 + tx];
  __syncthreads();
  for (int i = ty; i < 32; i += 8)
    Wt[(size_t)(n0 + i) * K + k0 + tx] = f2b(t[tx][i]);
}

// X(f32 [bt][389][512]) -> Xg(bf16 [bt*64][512]) + Xp(bf16 [bt*328(pad)][512])
__global__ __launch_bounds__(256) void convert_x(const float* __restrict__ X,
                                                 u16* __restrict__ Xg,
                                                 u16* __restrict__ Xp) {
  const size_t i = ((size_t)blockIdx.x * 256 + threadIdx.x) * 4;
  const f32x4 v = *(const f32x4*)(X + i);
  const size_t row = i >> 9;
  const int col = (int)(i & 511);
  const int bt = (int)(row / 389), n = (int)(row - (size_t)bt * 389);
  u16x4 w;
#pragma unroll
  for (int u = 0; u < 4; u++) w[u] = f2b(v[u]);
  u16* dst = (n < 64) ? (Xg + (((size_t)bt * 64 + n) << 9) + col)
                      : (Xp + (((size_t)bt * 328 + (n - 64)) << 9) + col);
  *(u16x4*)dst = w;
}

// ---------------------------------------------------------------------------
// GEMM: C = A @ Wt^T + bias. 128x128 tile, 4 waves (2x2 of 64x64), BK=64,
// global_load_lds(16B) with inverse-swizzled source + XOR-swizzled ds_read.
// Logical grid: x = N-panel (fast), y = M-block. XCD-chunked bijective
// remap (m204) so consecutive logical blocks (sharing an A row-panel and
// the L2-resident B panel) land on the SAME XCD.
// MODEs: 0 bf16 row-major | 1 bf16 row->bt*389+ofs+rr, skip rr>=aux
//        2 f32 d_out t-rows + bf16 copy | 3 f32 row-major | 4 bf16+relu
//        5 f32 += | 6 bf16 V^T [bt][h][d][kv] stride aux, LDS-staged
// ---------------------------------------------------------------------------
template <int MODE>
__global__ __launch_bounds__(256) void gemm_bt(
    const u16* __restrict__ A, const u16* __restrict__ Bt,
    const float* __restrict__ bias, float* outF, u16* outB,
    int M, int N, int K, int rows_per, int row_ofs, int aux) {
  __shared__ u16 SH[2][128 * 64];
  u16* As = &SH[0][0];
  u16* Bs = &SH[1][0];
  const int tid = threadIdx.x;
  const int lane = tid & 63, wid = tid >> 6;
  const int l4 = lane >> 4, l16 = lane & 15;
  // --- XCD-chunked bijective block remap (T1/m204) ---
  int bx, by;
  {
    const int gx = gridDim.x;
    const int nwg = gx * gridDim.y;
    const int b = blockIdx.y * gx + blockIdx.x;
    const int q = nwg >> 3, r = nwg & 7, x = b & 7, s = b >> 3;
    const int w = (x < r) ? (x * (q + 1) + s) : (r * (q + 1) + (x - r) * q + s);
    bx = w % gx; by = w / gx;
  }
  const int n0 = bx * 128, m0 = by * 128;
  const int wr = (wid >> 1) * 64, wc = (wid & 1) * 64;

  const int srow = lane >> 3;                  // row within 8-row group
  const int scol = 8 * ((lane & 7) ^ srow);    // inverse-swizzled col (elems)
  const u16* gA = A + (size_t)(m0 + wid * 32 + srow) * K + scol;
  const u16* gB = Bt + (size_t)(n0 + wid * 32 + srow) * K + scol;

  f32x4 acc[4][4] = {};

  for (int kk = 0; kk < K; kk += 64) {
    if (kk) __syncthreads();
#pragma unroll
    for (int c = 0; c < 4; c++) {
      async_cp16(As + (wid * 32 + c * 8) * 64, gA + (size_t)(c * 8) * K + kk);
      async_cp16(Bs + (wid * 32 + c * 8) * 64, gB + (size_t)(c * 8) * K + kk);
    }
    __syncthreads();
#pragma unroll
    for (int hh = 0; hh < 2; hh++) {
      const int sw = (((hh * 64 + l4 * 16) ^ ((l16 & 7) << 4)) >> 1);
      bf16x8 af[4], bfr[4];
#pragma unroll
      for (int i = 0; i < 4; i++)
        af[i] = *(const bf16x8*)(As + (wr + i * 16 + l16) * 64 + sw);
#pragma unroll
      for (int j = 0; j < 4; j++)
        bfr[j] = *(const bf16x8*)(Bs + (wc + j * 16 + l16) * 64 + sw);
#pragma unroll
      for (int i = 0; i < 4; i++)
#pragma unroll
        for (int j = 0; j < 4; j++)
          acc[i][j] = MFMA_B16(af[i], bfr[j], acc[i][j], 0, 0, 0);
    }
  }

  if constexpr (MODE == 6) {
    // Stage C in LDS, then write V^T with aligned 16B stores.
    __syncthreads();
    u16* cs = &SH[0][0];                       // 128x128 u16 = 32KB
#pragma unroll
    for (int j = 0; j < 4; j++) {
      const float bv = bias[n0 + wc + j * 16 + l16];
#pragma unroll
      for (int i = 0; i < 4; i++)
#pragma unroll
        for (int r = 0; r < 4; r++)
          cs[(wr + i * 16 + l4 * 4 + r) * 128 + wc + j * 16 + l16] =
              f2b(acc[i][j][r] + bv);
    }
    __syncthreads();
    const int c = tid & 127;
    const int kvh = (tid >> 7) * 64;
    const int gh = (n0 + c) >> 6, gd = (n0 + c) & 63;
#pragma unroll
    for (int g = 0; g < 8; g++) {
      const int row0 = m0 + kvh + g * 8;
      if (row0 >= M) break;
      const int bt0 = row0 / rows_per;
      const int rr = row0 - bt0 * rows_per;    // multiple of 8
      u16x8 w;
#pragma unroll
      for (int e = 0; e < 8; e++) w[e] = cs[(kvh + g * 8 + e) * 128 + c];
      *(u16x8*)(outB + (((size_t)bt0 * 8 + gh) * 64 + gd) * (size_t)aux +
                row_ofs + rr) = w;
    }
  } else {
#pragma unroll
    for (int j = 0; j < 4; j++) {
      const int col = n0 + wc + j * 16 + l16;
      const float bv = bias[col];
#pragma unroll
      for (int i = 0; i < 4; i++) {
#pragma unroll
        for (int r = 0; r < 4; r++) {
          const int row = m0 + wr + i * 16 + l4 * 4 + r;   // C layout m89/m91
          if (row >= M) continue;
          const float v = acc[i][j][r] + bv;
          if constexpr (MODE == 0) {
            outB[(size_t)row * N + col] = f2b(v);
          } else if constexpr (MODE == 1) {
            const int bt = row / rows_per, rr = row - bt * rows_per;
            if (rr < aux)
              outB[((size_t)bt * 389 + row_ofs + rr) * 512 + col] = f2b(v);
          } else if constexpr (MODE == 2) {
            const int bt = row >> 6, rr = row & 63;
            outF[((size_t)bt * 389 + rr) * 512 + col] = v;
            outB[(size_t)row * 512 + col] = f2b(v);
          } else if constexpr (MODE == 3) {
            outF[(size_t)row * N + col] = v;
          } else if constexpr (MODE == 4) {
            outB[(size_t)row * N + col] = f2b(v > 0.f ? v : 0.f);
          } else {  // 5
            outF[(size_t)row * N + col] += v;
          }
        }
      }
    }
  }
}

// ---------------------------------------------------------------------------
// Fused attention v4: flash online softmax in exp2 domain, no inter-wave
// barriers. Grid: (bt*8+h, q_pass). 4 waves x 16 q-rows; T2: +64-row tile B
// sharing K-fragments (tile B computed unconditionally; pad rows give small
// finite scores and stores are masked). Full chunks skip key-masking.
// ---------------------------------------------------------------------------
template <int QS, int MQ, int KS, int NK, int NKP, bool T2>
__global__ __launch_bounds__(256) void attn_fused(
    const u16* __restrict__ Q, const u16* __restrict__ Kb,
    const u16* __restrict__ Vt, u16* __restrict__ O) {
  constexpr int NF = NK / 64;                  // full (unmasked) chunks
  constexpr int PSTR = 72;
  constexpr float SCL = 0.18033688011112042f;  // 0.125 * log2(e)
  __shared__ __align__(16) u16 Pl[4][2][16 * PSTR];   // 18KB
  const int tid = threadIdx.x, lane = tid & 63, wid = tid >> 6;
  const int l4 = lane >> 4, l16 = lane & 15;
  const int bt = blockIdx.x >> 3, h = blockIdx.x & 7;
  u16* pw0 = &Pl[wid][0][0];
  u16* pw1 = &Pl[wid][1][0];
  const u16* vb = Vt + ((size_t)bt * 8 + h) * (size_t)(64 * NKP);
  const u16* kb = Kb + (size_t)bt * KS * 512 + h * 64;

  const int q0 = blockIdx.y * (T2 ? 128 : 64) + wid * 16;
  const u16* qp =
      Q + ((size_t)bt * QS + q0 + l16) * 512 + h * 64 + l4 * 8;
  const bf16x8 aq0A = *(const bf16x8*)qp;
  const bf16x8 aq1A = *(const bf16x8*)(qp + 32);
  bf16x8 aq0B = aq0A, aq1B = aq1A;
  if constexpr (T2) {
    aq0B = *(const bf16x8*)(qp + 32768);
    aq1B = *(const bf16x8*)(qp + 32768 + 32);
  }

  f32x4 m0v, m1v, sum0, sum1, o0[4], o1[4];
#pragma unroll
  for (int r = 0; r < 4; r++) {
    m0v[r] = -1e30f; m1v[r] = -1e30f; sum0[r] = 0.f; sum1[r] = 0.f;
  }
#pragma unroll
  for (int j = 0; j < 4; j++) {
    o0[j] = (f32x4){0.f, 0.f, 0.f, 0.f};
    o1[j] = (f32x4){0.f, 0.f, 0.f, 0.f};
  }

  auto chunk = [&](int k0, auto mc) {
    constexpr bool MASK = decltype(mc)::value;
    f32x4 sc0[4], sc1[4];
#pragma unroll
    for (int s = 0; s < 4; s++) {
      const u16* kp = kb + (size_t)(k0 + s * 16 + l16) * 512 + l4 * 8;
      const bf16x8 kf0 = *(const bf16x8*)kp;
      const bf16x8 kf1 = *(const bf16x8*)(kp + 32);
      f32x4 a = (f32x4){0.f, 0.f, 0.f, 0.f};
      a = MFMA_B16(aq0A, kf0, a, 0, 0, 0);
      a = MFMA_B16(aq1A, kf1, a, 0, 0, 0);
      sc0[s] = a;
      if constexpr (T2) {
        f32x4 bq = (f32x4){0.f, 0.f, 0.f, 0.f};
        bq = MFMA_B16(aq0B, kf0, bq, 0, 0, 0);
        bq = MFMA_B16(aq1B, kf1, bq, 0, 0, 0);
        sc1[s] = bq;
      }
    }
    // scale into exp2 domain (+ mask only in the last chunk)
#pragma unroll
    for (int s = 0; s < 4; s++) {
      bool vld = true;
      if constexpr (MASK) vld = (k0 + s * 16 + l16) < NK;
#pragma unroll
      for (int r = 0; r < 4; r++) {
        sc0[s][r] = vld ? sc0[s][r] * SCL : -1e30f;
        if constexpr (T2) sc1[s][r] = vld ? sc1[s][r] * SCL : -1e30f;
      }
    }
    f32x4 c0, c1;
#pragma unroll
    for (int r = 0; r < 4; r++) {
      c0[r] = fmaxf(fmaxf(sc0[0][r], sc0[1][r]), fmaxf(sc0[2][r], sc0[3][r]));
      if constexpr (T2)
        c1[r] = fmaxf(fmaxf(sc1[0][r], sc1[1][r]), fmaxf(sc1[2][r], sc1[3][r]));
    }
#pragma unroll
    for (int mk = 1; mk < 16; mk <<= 1)
#pragma unroll
      for (int r = 0; r < 4; r++) {
        c0[r] = fmaxf(c0[r], __shfl_xor(c0[r], mk));
        if constexpr (T2) c1[r] = fmaxf(c1[r], __shfl_xor(c1[r], mk));
      }
    // exact defer-max: rescale only if some lane's max grew
    float g = c0[0] - m0v[0];
#pragma unroll
    for (int r = 1; r < 4; r++) g = fmaxf(g, c0[r] - m0v[r]);
    if constexpr (T2)
#pragma unroll
      for (int r = 0; r < 4; r++) g = fmaxf(g, c1[r] - m1v[r]);
    if (__any(g > 0.f)) {
#pragma unroll
      for (int r = 0; r < 4; r++) {
        float mn = fmaxf(m0v[r], c0[r]);
        float f = ex2(m0v[r] - mn);
        m0v[r] = mn; sum0[r] *= f;
#pragma unroll
        for (int j = 0; j < 4; j++) o0[j][r] *= f;
        if constexpr (T2) {
          mn = fmaxf(m1v[r], c1[r]); f = ex2(m1v[r] - mn);
          m1v[r] = mn; sum1[r] *= f;
#pragma unroll
          for (int j = 0; j < 4; j++) o1[j][r] *= f;
        }
      }
    }
    // exp2, partial sums, P -> LDS transpose buffers (compiler bf16 casts)
#pragma unroll
    for (int s = 0; s < 4; s++)
#pragma unroll
      for (int r = 0; r < 4; r++) {
        const float e0 = ex2(sc0[s][r] - m0v[r]);
        sum0[r] += e0;
        ((__bf16*)pw0)[(l4 * 4 + r) * PSTR + s * 16 + l16] = (__bf16)e0;
        if constexpr (T2) {
          const float e1 = ex2(sc1[s][r] - m1v[r]);
          sum1[r] += e1;
          ((__bf16*)pw1)[(l4 * 4 + r) * PSTR + s * 16 + l16] = (__bf16)e1;
        }
      }
    asm volatile("s_waitcnt lgkmcnt(0)" ::: "memory");
    const bf16x8 apA0 = *(const bf16x8*)(pw0 + l16 * PSTR + l4 * 8);
    const bf16x8 apA1 = *(const bf16x8*)(pw0 + l16 * PSTR + 32 + l4 * 8);
    bf16x8 apB0 = apA0, apB1 = apA1;
    if constexpr (T2) {
      apB0 = *(const bf16x8*)(pw1 + l16 * PSTR + l4 * 8);
      apB1 = *(const bf16x8*)(pw1 + l16 * PSTR + 32 + l4 * 8);
    }
    __builtin_amdgcn_s_setprio(1);
#pragma unroll
    for (int j = 0; j < 4; j++) {
      const u16* vp = vb + (size_t)(j * 16 + l16) * NKP + k0 + l4 * 8;
      const bf16x8 v0 = *(const bf16x8*)vp;
      const bf16x8 v1 = *(const bf16x8*)(vp + 32);
      o0[j] = MFMA_B16(apA0, v0, o0[j], 0, 0, 0);
      o0[j] = MFMA_B16(apA1, v1, o0[j], 0, 0, 0);
      if constexpr (T2) {
        o1[j] = MFMA_B16(apB0, v0, o1[j], 0, 0, 0);
        o1[j] = MFMA_B16(apB1, v1, o1[j], 0, 0, 0);
      }
    }
    __builtin_amdgcn_s_setprio(0);
  };

  for (int ch = 0; ch < NF; ++ch) chunk(ch * 64, bc<false>{});
  chunk(NF * 64, bc<true>{});

  // final k-sum reduce + normalized store
#pragma unroll
  for (int mk = 1; mk < 16; mk <<= 1)
#pragma unroll
    for (int r = 0; r < 4; r++) {
      sum0[r] += __shfl_xor(sum0[r], mk);
      if constexpr (T2) sum1[r] += __shfl_xor(sum1[r], mk);
    }
  f32x4 inv0, inv1;
#pragma unroll
  for (int r = 0; r < 4; r++) {
    inv0[r] = 1.f / sum0[r];
    inv1[r] = T2 ? 1.f / sum1[r] : 0.f;
  }
#pragma unroll
  for (int j = 0; j < 4; j++)
#pragma unroll
    for (int r = 0; r < 4; r++) {
      const int qr = q0 + l4 * 4 + r;
      if (qr < MQ)
        O[((size_t)bt * QS + qr) * 512 + h * 64 + j * 16 + l16] =
            f2b(o0[j][r] * inv0[r]);
      if constexpr (T2)
        if (qr + 64 < MQ)
          O[((size_t)bt * QS + qr + 64) * 512 + h * 64 + j * 16 + l16] =
              f2b(o1[j][r] * inv1[r]);
    }
}

// ---------------------------------------------------------------------------
// LN1: y = LN(X_patch + y), y padded [bt*328+n]; also bf16 copy yb.
__global__ __launch_bounds__(256) void ln_res(const float* __restrict__ X,
                                              float* __restrict__ y,
                                              const float* g, const float* b,
                                              u16* __restrict__ yb) {
  const int p = blockIdx.x * 4 + (threadIdx.x >> 6);
  const int lane = threadIdx.x & 63;
  const int bt = p / 325, n = p - bt * 325;
  const size_t yrow = ((size_t)bt * 328 + n) * 512;
  const float* xr = X + ((size_t)bt * 389 + 64 + n) * 512 + lane * 8;
  const float* ar = y + yrow + lane * 8;
  float vv[8];
  {
    const f32x4 a0 = *(const f32x4*)xr, a1 = *(const f32x4*)(xr + 4);
    const f32x4 b0 = *(const f32x4*)ar, b1 = *(const f32x4*)(ar + 4);
#pragma unroll
    for (int u = 0; u < 4; u++) { vv[u] = a0[u] + b0[u]; vv[u + 4] = a1[u] + b1[u]; }
  }
  float s1 = 0.f, s2 = 0.f;
#pragma unroll
  for (int u = 0; u < 8; u++) { s1 += vv[u]; s2 += vv[u] * vv[u]; }
  for (int m = 1; m < 64; m <<= 1) { s1 += __shfl_xor(s1, m); s2 += __shfl_xor(s2, m); }
  const float mean = s1 * (1.f / 512.f);
  const float inv = rsqrtf(s2 * (1.f / 512.f) - mean * mean + 1e-5f);
  const int c0 = lane * 8;
  f32x4 o0, o1;
  u16x8 ob;
#pragma unroll
  for (int u = 0; u < 8; u++) {
    const float o = (vv[u] - mean) * inv * g[c0 + u] + b[c0 + u];
    if (u < 4) o0[u] = o; else o1[u - 4] = o;
    ob[u] = f2b(o);
  }
  *(f32x4*)(y + yrow + c0) = o0;
  *(f32x4*)(y + yrow + c0 + 4) = o1;
  *(u16x8*)(yb + yrow + c0) = ob;
}

// LN2: d_out patch rows = LN(y)
__global__ __launch_bounds__(256) void ln_out(const float* __restrict__ y,
                                              const float* g, const float* b,
                                              float* __restrict__ out) {
  const int p = blockIdx.x * 4 + (threadIdx.x >> 6);
  const int lane = threadIdx.x & 63;
  const int bt = p / 325, n = p - bt * 325;
  const float* yr = y + ((size_t)bt * 328 + n) * 512 + lane * 8;
  float vv[8];
  {
    const f32x4 a0 = *(const f32x4*)yr, a1 = *(const f32x4*)(yr + 4);
#pragma unroll
    for (int u = 0; u < 4; u++) { vv[u] = a0[u]; vv[u + 4] = a1[u]; }
  }
  float s1 = 0.f, s2 = 0.f;
#pragma unroll
  for (int u = 0; u < 8; u++) { s1 += vv[u]; s2 += vv[u] * vv[u]; }
  for (int m = 1; m < 64; m <<= 1) { s1 += __shfl_xor(s1, m); s2 += __shfl_xor(s2, m); }
  const float mean = s1 * (1.f / 512.f);
  const float inv = rsqrtf(s2 * (1.f / 512.f) - mean * mean + 1e-5f);
  const int c0 = lane * 8;
  f32x4 o0, o1;
#pragma unroll
  for (int u = 0; u < 8; u++) {
    const float o = (vv[u] - mean) * inv * g[c0 + u] + b[c0 + u];
    if (u < 4) o0[u] = o; else o1[u - 4] = o;
  }
  float* orow = out + ((size_t)bt * 389 + 64 + n) * 512 + c0;
  *(f32x4*)(orow) = o0;
  *(f32x4*)(orow + 4) = o1;
}

// ---------------------------------------------------------------------------
extern "C" void kernel_launch(void* const* d_in, const int* in_sizes, int n_in,
                              void* d_out, int out_size, void* d_ws,
                              size_t ws_size, hipStream_t stream) {
  (void)in_sizes; (void)n_in; (void)out_size; (void)ws_size;
  const float* X = (const float*)d_in[0];
  const float* W[8] = {(const float*)d_in[1],  (const float*)d_in[3],
                       (const float*)d_in[5],  (const float*)d_in[7],
                       (const float*)d_in[9],  (const float*)d_in[11],
                       (const float*)d_in[13], (const float*)d_in[15]};
  const float* Bv[8] = {(const float*)d_in[2],  (const float*)d_in[4],
                        (const float*)d_in[6],  (const float*)d_in[8],
                        (const float*)d_in[10], (const float*)d_in[12],
                        (const float*)d_in[14], (const float*)d_in[16]};
  const float* ff_w1 = (const float*)d_in[17];
  const float* ff_b1 = (const float*)d_in[18];
  const float* ff_w2 = (const float*)d_in[19];
  const float* ff_b2 = (const float*)d_in[20];
  const float* ln1_g = (const float*)d_in[21];
  const float* ln1_b = (const float*)d_in[22];
  const float* ln2_g = (const float*)d_in[23];
  const float* ln2_b = (const float*)d_in[24];
  float* out = (float*)d_out;
  char* ws = (char*)d_ws;

  // Sizes (bytes). Patch rows padded to 328/bt; +128-row staging pads.
  constexpr size_t szW   = 8388608;                      // 10 bf16 W^T
  constexpr size_t szXp  = (size_t)(62976 + 128) * 1024; // 64.6MB (also yb)
  constexpr size_t szQe  = (size_t)(12288 + 128) * 1024; // 12.7MB
  constexpr size_t szKe  = szXp;
  constexpr size_t szVte = (size_t)192 * 8 * 64 * 384 * 2;  // 75.5MB
  constexpr size_t szVtd = (size_t)192 * 8 * 64 * 448 * 2;  // 88.1MB
  // Regions (lifetime-disjoint):
  constexpr size_t o1 = szW;                  // Xp -> yb
  constexpr size_t o2 = o1 + szXp;            // Xg -> attn_e
  constexpr size_t o3 = o2 + szQe;            // tb
  constexpr size_t o4 = o3 + szQe;            // {Qe,Ke,Vte} -> {Qd,Kd} -> y
  constexpr size_t o5 = o4 + szQe + szKe + szVte;  // Vtd -> hb
  constexpr size_t o6 = o5 + szVtd;           // attn_d

  u16* wt     = (u16*)(ws);
  u16* Xp     = (u16*)(ws + o1);
  u16* yb     = (u16*)(ws + o1);
  u16* Xg     = (u16*)(ws + o2);
  u16* attn_e = (u16*)(ws + o2);
  u16* tb     = (u16*)(ws + o3);
  u16* Qe     = (u16*)(ws + o4);
  u16* Ke     = (u16*)(ws + o4 + szQe);
  u16* Vte    = (u16*)(ws + o4 + szQe + szKe);
  u16* Qd     = (u16*)(ws + o4);
  u16* Kd     = (u16*)(ws + o4 + szXp);
  float* y    = (float*)(ws + o4);
  u16* Vtd    = (u16*)(ws + o5);
  u16* hb     = (u16*)(ws + o5);
  u16* attn_d = (u16*)(ws + o6);

  u16* wt_p[8];
  for (int i = 0; i < 8; i++) wt_p[i] = wt + (size_t)i * 262144;
  u16* ff1t = wt + (size_t)8 * 262144;
  u16* ff2t = ff1t + (size_t)1048576;

  dim3 tblk(32, 8);
  for (int i = 0; i < 8; i++)
    transpose_w<<<dim3(16, 16), tblk, 0, stream>>>(W[i], wt_p[i], 512, 512);
  transpose_w<<<dim3(64, 16), tblk, 0, stream>>>(ff_w1, ff1t, 512, 2048);
  transpose_w<<<dim3(16, 64), tblk, 0, stream>>>(ff_w2, ff2t, 2048, 512);

  convert_x<<<37344, 256, 0, stream>>>(X, Xg, Xp);

  // Encoder: t = MHA(glob -> patch)
  gemm_bt<0><<<dim3(4, 96), 256, 0, stream>>>(Xg, wt_p[0], Bv[0], nullptr, Qe,
                                              12288, 512, 512, 0, 0, 0);
  gemm_bt<0><<<dim3(4, 492), 256, 0, stream>>>(Xp, wt_p[1], Bv[1], nullptr, Ke,
                                               62976, 512, 512, 0, 0, 0);
  gemm_bt<6><<<dim3(4, 492), 256, 0, stream>>>(Xp, wt_p[2], Bv[2], nullptr, Vte,
                                               62976, 512, 512, 328, 0, 384);
  attn_fused<64, 64, 328, 325, 384, false><<<dim3(1536, 1), 256, 0, stream>>>(
      Qe, Ke, Vte, attn_e);
  gemm_bt<2><<<dim3(4, 96), 256, 0, stream>>>(attn_e, wt_p[3], Bv[3], out, tb,
                                              12288, 512, 512, 0, 0, 0);

  // Decoder: x_kv = [t ; patch] via row-remap epilogues
  gemm_bt<0><<<dim3(4, 492), 256, 0, stream>>>(Xp, wt_p[4], Bv[4], nullptr, Qd,
                                               62976, 512, 512, 0, 0, 0);
  gemm_bt<1><<<dim3(4, 96), 256, 0, stream>>>(tb, wt_p[5], Bv[5], nullptr, Kd,
                                              12288, 512, 512, 64, 0, 64);
  gemm_bt<1><<<dim3(4, 492), 256, 0, stream>>>(Xp, wt_p[5], Bv[5], nullptr, Kd,
                                               62976, 512, 512, 328, 64, 325);
  gemm_bt<6><<<dim3(4, 96), 256, 0, stream>>>(tb, wt_p[6], Bv[6], nullptr, Vtd,
                                              12288, 512, 512, 64, 0, 448);
  gemm_bt<6><<<dim3(4, 492), 256, 0, stream>>>(Xp, wt_p[6], Bv[6], nullptr, Vtd,
                                               62976, 512, 512, 328, 64, 448);
  attn_fused<328, 325, 389, 389, 448, true><<<dim3(1536, 3), 256, 0, stream>>>(
      Qd, Kd, Vtd, attn_d);
  gemm_bt<3><<<dim3(4, 492), 256, 0, stream>>>(attn_d, wt_p[7], Bv[7], y,
                                               nullptr, 62976, 512, 512, 0, 0, 0);

  // LN1 (+residual), FF (4 row-chunks of 15744 = 123*128), LN2.
  ln_res<<<15600, 256, 0, stream>>>(X, y, ln1_g, ln1_b, yb);

  for (int c = 0; c < 4; c++) {
    const size_t ro = (size_t)c * 15744;
    gemm_bt<4><<<dim3(16, 123), 256, 0, stream>>>(
        yb + ro * 512, ff1t, ff_b1, nullptr, hb, 15744, 2048, 512, 0, 0, 0);
    gemm_bt<5><<<dim3(4, 123), 256, 0, stream>>>(
        hb, ff2t, ff_b2, y + ro * 512, nullptr, 15744, 512, 2048, 0, 0, 0);
  }
  ln_out<<<15600, 256, 0, stream>>>(y, ln2_g, ln2_b, out);
}